// Round 19
// baseline (326.685 us; speedup 1.0000x reference)
//
#include <hip/hip_runtime.h>
#include <hip/hip_bf16.h>
#include <math.h>

#define NBATCH 2
#define NSEQ   2048
#define NDIM   1024
#define NHEAD  16
#define NKVH   4
#define HDIM   64
#define KVD    256
#define NEXP   8
#define NINTER 512
#define NTOK   (NBATCH*NSEQ)
#define QKVN   1536
#define MAXTILE 40
#define RMS_EPS 1.1920929e-07f
#define LN_10000 9.210340371976184f
#define QSCALE (0.125f * 1.44269504088896f)   // 1/sqrt(64) * log2(e), folded into Q
#define DEFER_THR 11.5f                        // log2 domain ~= e^8
#define LOG2E 1.44269504088896f

typedef __attribute__((ext_vector_type(8))) short bf16x8;
typedef __attribute__((ext_vector_type(4))) short short4v;
typedef __attribute__((ext_vector_type(4))) float f32x4;

// compiler-cast bf16 conversion: RNE, clang fuses pairs into v_cvt_pk_bf16_f32
__device__ __forceinline__ short f2b(float f) {
  return __builtin_bit_cast(short, (__bf16)f);
}
__device__ __forceinline__ float b2f(short s) {
  unsigned u = ((unsigned)(unsigned short)s) << 16;
  return __builtin_bit_cast(float, u);
}
__device__ __forceinline__ float ex2(float x) {   // 2^x via v_exp_f32
  float r; asm("v_exp_f32 %0, %1" : "=v"(r) : "v"(x)); return r;
}
__device__ __forceinline__ void load_lds16(const short* g, short* l) {
  __builtin_amdgcn_global_load_lds((const __attribute__((address_space(1))) void*)g,
                                   (__attribute__((address_space(3))) void*)l, 16, 0, 0);
}

__device__ __forceinline__ float wred64(float v) {
#pragma unroll
  for (int m = 32; m >= 1; m >>= 1) v += __shfl_xor(v, m);
  return v;
}

// ---- W0: merged weight prep: cast wqkv/wproj (bids 0..2559) + transpose gate_up with
//      16-wide gate/up row interleave (bids 2560..4607) so gemm1 can fuse silu in-lane ----
__global__ __launch_bounds__(256) void k_w_prep(
    const float* __restrict__ cq, const float* __restrict__ ck,
    const float* __restrict__ cv, const float* __restrict__ pw,
    const float* __restrict__ gate_up,
    short* __restrict__ wqkv, short* __restrict__ wproj, short* __restrict__ wgu_t) {
  __shared__ short T[64*66];
  const int bid = blockIdx.x;
  const int t = threadIdx.x;
  if (bid < 2560) {
    const int row = bid;
    const int c = t * 4;
    const float* src; short* dst;
    if (row < 1024)      { src = cq + (size_t)row*NDIM;        dst = wqkv + (size_t)row*NDIM; }
    else if (row < 1280) { src = ck + (size_t)(row-1024)*NDIM; dst = wqkv + (size_t)row*NDIM; }
    else if (row < 1536) { src = cv + (size_t)(row-1280)*NDIM; dst = wqkv + (size_t)row*NDIM; }
    else                 { src = pw + (size_t)(row-1536)*NDIM; dst = wproj + (size_t)(row-1536)*NDIM; }
    float4 v = *(const float4*)(src + c);
    short4v o = {f2b(v.x), f2b(v.y), f2b(v.z), f2b(v.w)};
    *(short4v*)(dst + c) = o;
  } else {
    const int b2 = bid - 2560;
    const int kt = b2 & 15, nt = (b2 >> 4) & 15, e = b2 >> 8;
    const float* ie = gate_up + (size_t)e*1024*1024 + (size_t)(kt*64)*1024 + nt*64;
    short* we = wgu_t + (size_t)e*1024*1024;
    const int r = t >> 4, c = (t & 15) * 4;
#pragma unroll
    for (int p = 0; p < 4; ++p) {
      float4 v = *(const float4*)(ie + (size_t)(p*16 + r)*1024 + c);
      T[(p*16 + r)*66 + c + 0] = f2b(v.x);
      T[(p*16 + r)*66 + c + 1] = f2b(v.y);
      T[(p*16 + r)*66 + c + 2] = f2b(v.z);
      T[(p*16 + r)*66 + c + 3] = f2b(v.w);
    }
    __syncthreads();
#pragma unroll
    for (int p = 0; p < 4; ++p) {
      int rr = p*16 + r;
      int R = nt*64 + rr;            // original gate_up column (0..511 gate, 512..1023 up)
      int Rn = (R < 512) ? ((R & ~15)*2 + (R & 15))
                         : (((R - 512) & ~15)*2 + 16 + (R & 15));
      short4v o = {T[(c+0)*66 + rr], T[(c+1)*66 + rr], T[(c+2)*66 + rr], T[(c+3)*66 + rr]};
      *(short4v*)(we + (size_t)Rn*1024 + kt*64 + c) = o;
    }
  }
}

// ---------------- W1: per-expert transpose fp32 [KIN][NIN] -> bf16 [NIN][KIN] ----------------
__global__ __launch_bounds__(256) void k_w_transpose(
    const float* __restrict__ in, short* __restrict__ outp, int KIN, int NIN) {
  __shared__ short T[64*66];
  const int kt = blockIdx.x, nt = blockIdx.y, e = blockIdx.z;
  const float* ie = in + (size_t)e*KIN*NIN + (size_t)(kt*64)*NIN + nt*64;
  short* oe = outp + (size_t)e*NIN*KIN + (size_t)(nt*64)*KIN + kt*64;
  const int t = threadIdx.x;
  const int r = t >> 4, c = (t & 15) * 4;
#pragma unroll
  for (int p = 0; p < 4; ++p) {
    float4 v = *(const float4*)(ie + (size_t)(p*16 + r)*NIN + c);
    T[(p*16 + r)*66 + c + 0] = f2b(v.x);
    T[(p*16 + r)*66 + c + 1] = f2b(v.y);
    T[(p*16 + r)*66 + c + 2] = f2b(v.z);
    T[(p*16 + r)*66 + c + 3] = f2b(v.w);
  }
  __syncthreads();
#pragma unroll
  for (int p = 0; p < 4; ++p) {
    int rr = p*16 + r;
    short4v o = {T[(c+0)*66 + rr], T[(c+1)*66 + rr], T[(c+2)*66 + rr], T[(c+3)*66 + rr]};
    *(short4v*)(oe + (size_t)rr*KIN + c) = o;
  }
}

// ---------------- K1: xr(bf16) = mix; n(bf16) = rmsnorm ----------------
__global__ __launch_bounds__(256) void k_resid_rms(
    const float* __restrict__ x, const float* __restrict__ x0,
    const float* __restrict__ rmix, short* __restrict__ xr, short* __restrict__ nrm) {
  const int row = blockIdx.x;
  const int t = threadIdx.x;
  const int d = t * 4;
  const size_t base = (size_t)row * NDIM + d;
  float4 a  = *(const float4*)(x  + base);
  float4 b  = *(const float4*)(x0 + base);
  float4 m0 = *(const float4*)(rmix + d);
  float4 m1 = *(const float4*)(rmix + NDIM + d);
  float4 r;
  r.x = m0.x*a.x + m1.x*b.x;
  r.y = m0.y*a.y + m1.y*b.y;
  r.z = m0.z*a.z + m1.z*b.z;
  r.w = m0.w*a.w + m1.w*b.w;
  float ss = r.x*r.x + r.y*r.y + r.z*r.z + r.w*r.w;
  ss = wred64(ss);
  __shared__ float wsum[4];
  if ((t & 63) == 0) wsum[t >> 6] = ss;
  __syncthreads();
  float tot = wsum[0] + wsum[1] + wsum[2] + wsum[3];
  float rms = rsqrtf(tot * (1.0f/NDIM) + RMS_EPS);
  short4v xo = {f2b(r.x), f2b(r.y), f2b(r.z), f2b(r.w)};
  short4v no = {f2b(r.x*rms), f2b(r.y*rms), f2b(r.z*rms), f2b(r.w*rms)};
  *(short4v*)(xr + base) = xo;
  *(short4v*)(nrm + base) = no;
}

// ---------------- K2: MFMA GEMM 128x128, BK=32, 2-phase double-buffered staging ----------------
// MODE 0: plain rows -> bf16. MODE 1: gather-A -> bf16. MODE 2: compact-A -> scatter-add fp32.
// MODE 3: gather-A, interleaved gate/up B -> fused silu, compact bf16 h [slots][512].
// MODE 4: QKV fused epilogue — Q/K waves: per-row rmsnorm(64)+rope(+qgain via mscale) -> Cb;
//         V waves: raw transposed store to vbT (passed via Cf).
template <int MODE>
__global__ __launch_bounds__(256) void k_gemm_mfma(
    const short* __restrict__ A, int lda,
    const short* __restrict__ Bw, int K, int N,
    short* __restrict__ Cb, float* __restrict__ Cf, int ldc,
    const int* __restrict__ rowmap, const int* __restrict__ tiletab,
    const int* __restrict__ meta, const float* __restrict__ mscale) {
  __shared__ short sA[2][128*32];
  __shared__ short sB[2][128*32];
  int row0, end = 0x7fffffff, e = 0;
  if (MODE == 0 || MODE == 4) {
    row0 = blockIdx.y * 128;
  } else {
    e = tiletab[2*blockIdx.y];
    if (e < 0) return;
    row0 = tiletab[2*blockIdx.y + 1];
    end = meta[1 + e];
  }
  const int t = threadIdx.x;
  const int w = t >> 6, l = t & 63;
  const int wr = (w >> 1) * 64, wc = (w & 1) * 64;
  const int lrow = l & 15, lk8 = (l >> 4) * 8;
  const int srow0 = w*16 + (l >> 2);
  const int scol = (l & 3) * 8;
  const short* Bp = Bw + (size_t)e * N * K + (size_t)(blockIdx.x * 128) * K;
  const short* gA0;
  const short* gA1;
  if (MODE == 1 || MODE == 3) {
    int s0 = row0 + srow0;      if (s0 >= NTOK) s0 = NTOK - 1;
    int s1 = row0 + 64 + srow0; if (s1 >= NTOK) s1 = NTOK - 1;
    gA0 = A + (size_t)rowmap[s0] * lda + scol;
    gA1 = A + (size_t)rowmap[s1] * lda + scol;
  } else {
    gA0 = A + (size_t)(row0 + srow0) * lda + scol;
    gA1 = A + (size_t)(row0 + 64 + srow0) * lda + scol;
  }
  const short* gB0 = Bp + (size_t)srow0 * K + scol;
  const short* gB1 = Bp + (size_t)(64 + srow0) * K + scol;
  const int lo0 = (w*16)*32;          // wave-uniform LDS offsets
  const int lo1 = (64 + w*16)*32;
  f32x4 acc[4][4];
#pragma unroll
  for (int m = 0; m < 4; ++m)
#pragma unroll
    for (int n = 0; n < 4; ++n) acc[m][n] = 0.f;
  // prologue: stage tile 0 into buf 0
  load_lds16(gA0, sA[0] + lo0);
  load_lds16(gA1, sA[0] + lo1);
  load_lds16(gB0, sB[0] + lo0);
  load_lds16(gB1, sB[0] + lo1);
  gA0 += 32; gA1 += 32; gB0 += 32; gB1 += 32;
  int cur = 0;
  for (int k0 = 0; k0 < K; k0 += 32) {
    __syncthreads();                 // drains vmcnt: buf[cur] ready; prior reads of buf[cur^1] done
    if (k0 + 32 < K) {               // prefetch next tile into the other buffer
      load_lds16(gA0, sA[cur^1] + lo0);
      load_lds16(gA1, sA[cur^1] + lo1);
      load_lds16(gB0, sB[cur^1] + lo0);
      load_lds16(gB1, sB[cur^1] + lo1);
      gA0 += 32; gA1 += 32; gB0 += 32; gB1 += 32;
    }
    bf16x8 af[4], bfr[4];
#pragma unroll
    for (int m = 0; m < 4; ++m)
      af[m] = *(const bf16x8*)&sA[cur][(wr + m*16 + lrow)*32 + lk8];
#pragma unroll
    for (int n = 0; n < 4; ++n)
      bfr[n] = *(const bf16x8*)&sB[cur][(wc + n*16 + lrow)*32 + lk8];
    __builtin_amdgcn_s_setprio(1);
#pragma unroll
    for (int m = 0; m < 4; ++m)
#pragma unroll
      for (int n = 0; n < 4; ++n)
        acc[m][n] = __builtin_amdgcn_mfma_f32_16x16x32_bf16(af[m], bfr[n], acc[m][n], 0, 0, 0);
    __builtin_amdgcn_s_setprio(0);
    cur ^= 1;
  }
  const int col0 = blockIdx.x * 128;
  if (MODE <= 1) {
#pragma unroll
    for (int m = 0; m < 4; ++m) {
#pragma unroll
      for (int r = 0; r < 4; ++r) {
        int rr = row0 + wr + m*16 + (l >> 4)*4 + r;
        if (rr < end) {
#pragma unroll
          for (int n = 0; n < 4; ++n)
            Cb[(size_t)rr * ldc + col0 + wc + n*16 + lrow] = f2b(acc[m][n][r]);
        }
      }
    }
  } else if (MODE == 2) {
#pragma unroll
    for (int m = 0; m < 4; ++m) {
#pragma unroll
      for (int r = 0; r < 4; ++r) {
        int slot = row0 + wr + m*16 + (l >> 4)*4 + r;
        if (slot < end) {
          int tok = rowmap[slot];
#pragma unroll
          for (int n = 0; n < 4; ++n) {
            int cc = col0 + wc + n*16 + lrow;
            Cf[(size_t)tok * ldc + cc] += mscale[cc] * acc[m][n][r];
          }
        }
      }
    }
  } else if (MODE == 3) {   // interleaved gate/up pairs -> h = silu(g)*u, compact [slots][512]
    const int fbBase = (col0 + wc) >> 5;
#pragma unroll
    for (int m = 0; m < 4; ++m) {
#pragma unroll
      for (int r = 0; r < 4; ++r) {
        int slot = row0 + wr + m*16 + (l >> 4)*4 + r;
        if (slot < end) {
#pragma unroll
          for (int p = 0; p < 2; ++p) {
            float gg = acc[m][2*p][r], uu = acc[m][2*p+1][r];
            float sg = 1.0f / (1.0f + ex2(-LOG2E * gg));
            Cb[(size_t)slot * NINTER + (fbBase + p)*16 + lrow] = f2b(gg * sg * uu);
          }
        }
      }
    }
  } else {   // MODE 4: fused QKV epilogue
    const int colw = col0 + wc;              // wave-uniform
    if (colw < 1280) {
      // Q (colw<1024) or K head: per-row rmsnorm over this wave's 64 dims + rope
      const bool isQ = (colw < 1024);
      const float qsc = isQ ? (mscale[colw >> 6] * QSCALE) : 1.0f;
      const float c0 = expf(-(float)lrow * (LN_10000/32.0f));
      const float c1 = expf(-(float)(16 + lrow) * (LN_10000/32.0f));
#pragma unroll
      for (int m = 0; m < 4; ++m) {
#pragma unroll
        for (int r = 0; r < 4; ++r) {
          int rowg = row0 + wr + m*16 + (l >> 4)*4 + r;
          float ss = 0.f;
#pragma unroll
          for (int n = 0; n < 4; ++n) ss += acc[m][n][r]*acc[m][n][r];
          ss += __shfl_xor(ss, 1); ss += __shfl_xor(ss, 2);
          ss += __shfl_xor(ss, 4); ss += __shfl_xor(ss, 8);
          float rr2 = rsqrtf(ss * (1.0f/64.0f) + RMS_EPS);
          float s = (float)(rowg & (NSEQ - 1));
          float fr0 = s * c0, fr1 = s * c1;
          float co0 = cosf(fr0), si0 = sinf(fr0);
          float co1 = cosf(fr1), si1 = sinf(fr1);
          float v0 = acc[m][0][r]*rr2, v1 = acc[m][1][r]*rr2;
          float v2 = acc[m][2][r]*rr2, v3 = acc[m][3][r]*rr2;
          short* cp = Cb + (size_t)rowg * ldc + colw + lrow;
          cp[0]  = f2b((v0*co0 + v2*si0) * qsc);
          cp[16] = f2b((v1*co1 + v3*si1) * qsc);
          cp[32] = f2b((v2*co0 - v0*si0) * qsc);
          cp[48] = f2b((v3*co1 - v1*si1) * qsc);
        }
      }
    } else {
      // V head: raw, transposed store to vbT[(b*NKVH+kh)*HDIM + d][token]
      short* vbT = (short*)Cf;
      const int kh2 = (colw - 1280) >> 6;
      const int bb = row0 >> 11;
      const int sbase = (row0 & (NSEQ - 1)) + wr;
#pragma unroll
      for (int n = 0; n < 4; ++n) {
        int d = n*16 + lrow;
        size_t colbase = ((size_t)(bb*NKVH + kh2)*HDIM + d) * NSEQ;
#pragma unroll
        for (int m = 0; m < 4; ++m) {
          int s0 = sbase + m*16 + (l >> 4)*4;
          short4v o = {f2b(acc[m][n][0]), f2b(acc[m][n][1]),
                       f2b(acc[m][n][2]), f2b(acc[m][n][3])};
          *(short4v*)(vbT + colbase + s0) = o;
        }
      }
    }
  }
}

// ---------------- K4: causal flash attention, swapped-QK^T MFMA, 128-row Q tiles ----------------
// v8 (round-18, proven 52.5us): in-register P (pf = concat of lane-local packed P), V LDS
// key-columns sigma-permuted; balanced qt remap, dbuf reg-staged K/V, defer-max, setprio,
// hoisted K-fragments. No Ps LDS (36.9KB).
__global__ __launch_bounds__(256) void k_attn_mfma(
    const short* __restrict__ qkv, const short* __restrict__ vbT, short* __restrict__ y) {
  __shared__ short Ks[2][64*72];   // [key][dim]
  __shared__ short Vt[2][64*72];   // [dim][key], key-cols sigma-permuted
  const int t = threadIdx.x;
  const int l = t & 63, w = t >> 6;
  const int lrow = l & 15, g = l >> 4, lk8 = g * 8;
  const int bid = blockIdx.x;
  int qt = bid & 15;
  const int h = (bid >> 4) & 15, b = bid >> 8;
  if (b & 1) qt = 15 - qt;   // balance: co-resident pairs sum to constant tile count
  const int kh = h >> 2;
  bf16x8 qf[2][2];   // [qra][k-half]; Q as B-operand (col = q-row)
#pragma unroll
  for (int qra = 0; qra < 2; ++qra) {
    int qrow_g = b*NSEQ + qt*128 + qra*64 + w*16 + lrow;
#pragma unroll
    for (int hf = 0; hf < 2; ++hf)
      qf[qra][hf] = *(const bf16x8*)(qkv + (size_t)qrow_g*QKVN + h*HDIM + hf*32 + lk8);
  }
  const int r0a = t >> 3;
  const int d0a = (t & 7) * 8;
  const int mseg = t & 7;
  // sigma-permuted V column base for this 8-key chunk
  const int vb0 = (mseg >> 2)*32 + (mseg & 1)*16 + ((mseg >> 1) & 1)*4;
  const short* kgbase = qkv + 1024 + (size_t)kh*HDIM;
  const short* vgbase = vbT + (size_t)((b*NKVH + kh)*HDIM)*NSEQ;
  bf16x8 kr0, kr1, vr0, vr1;
#define LOADKV(KT) do { \
    kr0 = *(const bf16x8*)(kgbase + (size_t)(b*NSEQ + (KT)*64 + r0a)*QKVN + d0a); \
    kr1 = *(const bf16x8*)(kgbase + (size_t)(b*NSEQ + (KT)*64 + r0a + 32)*QKVN + d0a); \
    vr0 = *(const bf16x8*)(vgbase + (size_t)r0a*NSEQ + (KT)*64 + d0a); \
    vr1 = *(const bf16x8*)(vgbase + (size_t)(r0a + 32)*NSEQ + (KT)*64 + d0a); \
  } while (0)
  float m_i[2] = {-INFINITY, -INFINITY};
  float l_i[2] = {0.f, 0.f};
  f32x4 O[2][4];
#pragma unroll
  for (int qra = 0; qra < 2; ++qra)
#pragma unroll
    for (int db = 0; db < 4; ++db) O[qra][db] = 0.f;
  const int ktmax = 2*qt + 1;
  LOADKV(0);
  for (int kt = 0; kt <= ktmax; ++kt) {
    const int buf = kt & 1;
    *(bf16x8*)&Ks[buf][r0a*72 + d0a] = kr0;
    *(bf16x8*)&Ks[buf][(r0a + 32)*72 + d0a] = kr1;
    {  // V: sigma-permuted columns -> two b64 writes per 8-key chunk per row
      short4v* v0p = (short4v*)&vr0;
      short4v* v1p = (short4v*)&vr1;
      *(short4v*)&Vt[buf][r0a*72 + vb0]            = v0p[0];
      *(short4v*)&Vt[buf][r0a*72 + vb0 + 8]        = v0p[1];
      *(short4v*)&Vt[buf][(r0a + 32)*72 + vb0]     = v1p[0];
      *(short4v*)&Vt[buf][(r0a + 32)*72 + vb0 + 8] = v1p[1];
    }
    __syncthreads();
    if (kt < ktmax) LOADKV(kt + 1);   // async prefetch: lands during compute below
    // K fragments are qra-invariant: read ONCE per tile
    bf16x8 kf[4][2];
#pragma unroll
    for (int nb = 0; nb < 4; ++nb) {
      kf[nb][0] = *(const bf16x8*)&Ks[buf][(nb*16 + lrow)*72 + lk8];
      kf[nb][1] = *(const bf16x8*)&Ks[buf][(nb*16 + lrow)*72 + 32 + lk8];
    }
    const int qra0 = (kt == ktmax) ? 1 : 0;   // q-rows 0..63 fully masked on last tile
    bf16x8 pf[2][2];
#pragma unroll
    for (int qra = 0; qra < 2; ++qra) {
      if (qra >= qra0) {
        f32x4 sc[4];
#pragma unroll
        for (int nb = 0; nb < 4; ++nb) sc[nb] = 0.f;
        __builtin_amdgcn_s_setprio(1);
#pragma unroll
        for (int nb = 0; nb < 4; ++nb) {
          sc[nb] = __builtin_amdgcn_mfma_f32_16x16x32_bf16(kf[nb][0], qf[qra][0], sc[nb], 0, 0, 0);
          sc[nb] = __builtin_amdgcn_mfma_f32_16x16x32_bf16(kf[nb][1], qf[qra][1], sc[nb], 0, 0, 0);
        }
        __builtin_amdgcn_s_setprio(0);
        if (kt >= 2*qt) {   // diagonal tiles: elementwise causal mask
          int qg = qt*128 + qra*64 + w*16 + lrow;
#pragma unroll
          for (int nb = 0; nb < 4; ++nb)
#pragma unroll
            for (int r = 0; r < 4; ++r)
              if (kt*64 + nb*16 + g*4 + r > qg) sc[nb][r] = -INFINITY;
        }
        float rm = sc[0][0];
#pragma unroll
        for (int nb = 0; nb < 4; ++nb)
#pragma unroll
          for (int r = 0; r < 4; ++r) rm = fmaxf(rm, sc[nb][r]);
        rm = fmaxf(rm, __shfl_xor(rm, 16));
        rm = fmaxf(rm, __shfl_xor(rm, 32));
        if (!__all(rm <= m_i[qra] + DEFER_THR)) {
          float mn = fmaxf(m_i[qra], rm);
          float fac = ex2(m_i[qra] - mn);
          l_i[qra] *= fac;
          m_i[qra] = mn;
#pragma unroll
          for (int r = 0; r < 4; ++r) {
            float ff = __shfl(fac, g*4 + r);
#pragma unroll
            for (int db = 0; db < 4; ++db) O[qra][db][r] *= ff;
          }
        }
        float rs = 0.f;
#pragma unroll
        for (int nb = 0; nb < 4; ++nb) {
#pragma unroll
          for (int r = 0; r < 4; ++r) {
            float p = ex2(sc[nb][r] - m_i[qra]);
            sc[nb][r] = p;
            rs += p;
          }
        }
        rs += __shfl_xor(rs, 16);
        rs += __shfl_xor(rs, 32);
        l_i[qra] += rs;
        // ---- in-register P: pf[H] = concat(pk[2H], pk[2H+1]), fully lane-local ----
        unsigned pk[4][2];
#pragma unroll
        for (int nb = 0; nb < 4; ++nb) {
          asm("v_cvt_pk_bf16_f32 %0, %1, %2" : "=v"(pk[nb][0]) : "v"(sc[nb][0]), "v"(sc[nb][1]));
          asm("v_cvt_pk_bf16_f32 %0, %1, %2" : "=v"(pk[nb][1]) : "v"(sc[nb][2]), "v"(sc[nb][3]));
        }
#pragma unroll
        for (int H = 0; H < 2; ++H) {
          union { unsigned u[4]; bf16x8 v; } P;
          P.u[0] = pk[2*H][0];
          P.u[1] = pk[2*H][1];
          P.u[2] = pk[2*H+1][0];
          P.u[3] = pk[2*H+1][1];
          pf[qra][H] = P.v;
        }
      }
    }
    __builtin_amdgcn_s_setprio(1);
#pragma unroll
    for (int db = 0; db < 4; ++db) {
      bf16x8 vf0 = *(const bf16x8*)&Vt[buf][(db*16 + lrow)*72 + lk8];
      bf16x8 vf1 = *(const bf16x8*)&Vt[buf][(db*16 + lrow)*72 + 32 + lk8];
      if (qra0 == 0) {
        O[0][db] = __builtin_amdgcn_mfma_f32_16x16x32_bf16(pf[0][0], vf0, O[0][db], 0, 0, 0);
        O[0][db] = __builtin_amdgcn_mfma_f32_16x16x32_bf16(pf[0][1], vf1, O[0][db], 0, 0, 0);
      }
      O[1][db] = __builtin_amdgcn_mfma_f32_16x16x32_bf16(pf[1][0], vf0, O[1][db], 0, 0, 0);
      O[1][db] = __builtin_amdgcn_mfma_f32_16x16x32_bf16(pf[1][1], vf1, O[1][db], 0, 0, 0);
    }
    __builtin_amdgcn_s_setprio(0);
  }
#undef LOADKV
#pragma unroll
  for (int qra = 0; qra < 2; ++qra) {
    float linv = 1.0f / l_i[qra];
#pragma unroll
    for (int r = 0; r < 4; ++r) {
      float inv = __shfl(linv, g*4 + r);
      int rowo = b*NSEQ + qt*128 + qra*64 + w*16 + g*4 + r;
#pragma unroll
      for (int db = 0; db < 4; ++db)
        y[(size_t)rowo*NDIM + h*HDIM + db*16 + lrow] = f2b(O[qra][db][r] * inv);
    }
  }
}

// --------- K5: x2/v_next -> out(f32) ; mbuf = rmsnorm(x2) bf16 ; block 0 also routes ---------
__global__ __launch_bounds__(256) void k_fuse_vel(
    const short* __restrict__ xr, const short* __restrict__ aout,
    const float* __restrict__ vel, const float* __restrict__ ascale,
    const float* __restrict__ mu, float* __restrict__ out, short* __restrict__ mbuf,
    const int* __restrict__ eids, int* __restrict__ rowmap,
    int* __restrict__ tiletab, int* __restrict__ meta) {
  const int row = blockIdx.x;
  const int t = threadIdx.x;
  const int d = t * 4;
  const size_t base = (size_t)row * NDIM + d;
  short4v a4 = *(const short4v*)(xr + base);
  short4v o4 = *(const short4v*)(aout + base);
  float4 vv = *(const float4*)(vel + base);
  float4 as = *(const float4*)(ascale + d);
  float4 mu4 = *(const float4*)(mu + d);
  float xs[4], vns[4];
  const float asl[4] = {as.x, as.y, as.z, as.w};
  const float mul[4] = {mu4.x, mu4.y, mu4.z, mu4.w};
  const float vvl[4] = {vv.x, vv.y, vv.z, vv.w};
#pragma unroll
  for (int i = 0; i < 4; ++i) {
    float x1 = b2f(a4[i]) + asl[i] * b2f(o4[i]);
    float muc = fminf(fmaxf(mul[i], 0.5f), 1.5f);
    float vn = fminf(fmaxf(0.95f*vvl[i] - 0.3f*(x1 - muc), -3.f), 3.f);
    xs[i] = x1 + 0.01f*vn;
    vns[i] = vn;
  }
  float4 x2 = {xs[0], xs[1], xs[2], xs[3]};
  float4 vnq = {vns[0], vns[1], vns[2], vns[3]};
  *(float4*)(out + base) = x2;
  *(float4*)(out + (size_t)NTOK*NDIM + base) = vnq;
  float ss = xs[0]*xs[0] + xs[1]*xs[1] + xs[2]*xs[2] + xs[3]*xs[3];
  ss = wred64(ss);
  __shared__ float wsum[4];
  if ((t & 63) == 0) wsum[t >> 6] = ss;
  __syncthreads();
  float tot = wsum[0] + wsum[1] + wsum[2] + wsum[3];
  float rms = rsqrtf(tot * (1.0f/NDIM) + RMS_EPS);
  short4v m4 = {f2b(xs[0]*rms), f2b(xs[1]*rms), f2b(xs[2]*rms), f2b(xs[3]*rms)};
  *(short4v*)(mbuf + base) = m4;
  // ---- block 0: token routing (consumed by gemm1/gemm2, which launch after this kernel) ----
  if (blockIdx.x == 0) {
    __shared__ int cnt[NEXP];
    __shared__ int ctr[NEXP];
    if (t < NEXP) cnt[t] = 0;
    __syncthreads();
    for (int i = t; i < NTOK; i += 256) atomicAdd(&cnt[eids[i]], 1);
    __syncthreads();
    if (t == 0) {
      int off = 0, tile = 0;
      for (int e = 0; e < NEXP; ++e) {
        ctr[e] = off;
        int nt_e = (cnt[e] + 127) >> 7;
        for (int j = 0; j < nt_e; ++j) { tiletab[2*tile] = e; tiletab[2*tile+1] = off + j*128; ++tile; }
        off += cnt[e];
        meta[1 + e] = off;
      }
      meta[0] = tile;
      for (int j = tile; j < MAXTILE; ++j) { tiletab[2*j] = -1; tiletab[2*j+1] = 0; }
    }
    __syncthreads();
    for (int i = t; i < NTOK; i += 256) {
      int e = eids[i];
      int slot = atomicAdd(&ctr[e], 1);
      rowmap[slot] = i;
    }
  }
}

extern "C" void kernel_launch(void* const* d_in, const int* in_sizes, int n_in,
                              void* d_out, int out_size, void* d_ws, size_t ws_size,
                              hipStream_t stream) {
  const float* x      = (const float*)d_in[0];
  const float* x0     = (const float*)d_in[1];
  const float* vel    = (const float*)d_in[2];
  const float* rmix   = (const float*)d_in[3];
  const float* ascale = (const float*)d_in[4];
  const float* mscale = (const float*)d_in[5];
  const float* cq_w   = (const float*)d_in[6];
  const float* ck_w   = (const float*)d_in[7];
  const float* cv_w   = (const float*)d_in[8];
  const float* proj_w = (const float*)d_in[9];
  const float* q_gain = (const float*)d_in[10];
  const float* mu     = (const float*)d_in[11];
  const float* gate_up= (const float*)d_in[12];
  const float* down   = (const float*)d_in[13];
  const int*   eids   = (const int*)d_in[14];
  float* out = (float*)d_out;
  char* base = (char*)d_ws;

  const size_t MB = 1024*1024;
  short* wqkv  = (short*)base;            // [0,3)
  short* wproj = (short*)(base + 3*MB);   // [3,5)
  int*   rowmap  = (int*)(base + 5*MB);   // [5,6)
  int*   tiletab = rowmap + NTOK;
  int*   meta    = tiletab + 2*MAXTILE;
  short* wgu_t = (short*)(base + 6*MB);   // [6,22): interleaved gate/up weights
  short* xr    = (short*)(base + 22*MB);  // [22,30): xr -> hbuf after fuse_vel
  short* hbuf  = xr;
  short* nbuf  = (short*)(base + 30*MB);  // [30,38): n -> y -> mbuf -> wdn_t
  short* ybuf  = nbuf;
  short* mbuf  = nbuf;
  short* wdn_t = nbuf;
  short* qkv   = (short*)(base + 38*MB);  // [38,50): qkv -> aout after attn
  short* aout  = qkv;
  short* vbT   = (short*)(base + 50*MB);  // [50,52)

  k_w_prep<<<4608, 256, 0, stream>>>(cq_w, ck_w, cv_w, proj_w, gate_up, wqkv, wproj, wgu_t);
  k_resid_rms<<<NTOK, 256, 0, stream>>>(x, x0, rmix, xr, nbuf);
  k_gemm_mfma<4><<<dim3(QKVN/128, NTOK/128), 256, 0, stream>>>(
      nbuf, NDIM, wqkv, NDIM, QKVN, qkv, (float*)vbT, QKVN, nullptr, nullptr, nullptr, q_gain);
  k_attn_mfma<<<NBATCH*NHEAD*(NSEQ/128), 256, 0, stream>>>(qkv, vbT, ybuf);
  k_gemm_mfma<0><<<dim3(NDIM/128, NTOK/128), 256, 0, stream>>>(
      ybuf, NDIM, wproj, NDIM, NDIM, aout, nullptr, NDIM, nullptr, nullptr, nullptr, nullptr);
  k_fuse_vel<<<NTOK, 256, 0, stream>>>(xr, aout, vel, ascale, mu, out, mbuf,
                                       eids, rowmap, tiletab, meta);
  k_gemm_mfma<3><<<dim3(1024/128, MAXTILE), 256, 0, stream>>>(
      mbuf, NDIM, wgu_t, NDIM, 1024, hbuf, nullptr, NINTER, rowmap, tiletab, meta, nullptr);
  k_w_transpose<<<dim3(8, 16, 8), 256, 0, stream>>>(down, wdn_t, 512, 1024);
  k_gemm_mfma<2><<<dim3(NDIM/128, MAXTILE), 256, 0, stream>>>(
      hbuf, NINTER, wdn_t, NINTER, NDIM, nullptr, out, NDIM, rowmap, tiletab, meta, mscale);
}

// Round 20
// 214.502 us; speedup vs baseline: 1.5230x; 1.5230x over previous
//
#include <hip/hip_runtime.h>
#include <hip/hip_bf16.h>
#include <math.h>

#define NBATCH 2
#define NSEQ   2048
#define NDIM   1024
#define NHEAD  16
#define NKVH   4
#define HDIM   64
#define KVD    256
#define NEXP   8
#define NINTER 512
#define NTOK   (NBATCH*NSEQ)
#define QKVN   1536
#define MAXTILE 40
#define RMS_EPS 1.1920929e-07f
#define LN_10000 9.210340371976184f
#define QSCALE (0.125f * 1.44269504088896f)   // 1/sqrt(64) * log2(e), folded into Q
#define DEFER_THR 11.5f                        // log2 domain ~= e^8
#define LOG2E 1.44269504088896f

typedef __attribute__((ext_vector_type(8))) short bf16x8;
typedef __attribute__((ext_vector_type(4))) short short4v;
typedef __attribute__((ext_vector_type(4))) float f32x4;

// compiler-cast bf16 conversion: RNE, clang fuses pairs into v_cvt_pk_bf16_f32
__device__ __forceinline__ short f2b(float f) {
  return __builtin_bit_cast(short, (__bf16)f);
}
__device__ __forceinline__ float b2f(short s) {
  unsigned u = ((unsigned)(unsigned short)s) << 16;
  return __builtin_bit_cast(float, u);
}
__device__ __forceinline__ float ex2(float x) {   // 2^x via v_exp_f32
  float r; asm("v_exp_f32 %0, %1" : "=v"(r) : "v"(x)); return r;
}
__device__ __forceinline__ void load_lds16(const short* g, short* l) {
  __builtin_amdgcn_global_load_lds((const __attribute__((address_space(1))) void*)g,
                                   (__attribute__((address_space(3))) void*)l, 16, 0, 0);
}

__device__ __forceinline__ float wred64(float v) {
#pragma unroll
  for (int m = 32; m >= 1; m >>= 1) v += __shfl_xor(v, m);
  return v;
}

// ---- W0: merged weight prep: cast wqkv/wproj (bids 0..2559) + transpose gate_up with
//      16-wide gate/up row interleave (bids 2560..4607) so gemm1 can fuse silu in-lane ----
__global__ __launch_bounds__(256) void k_w_prep(
    const float* __restrict__ cq, const float* __restrict__ ck,
    const float* __restrict__ cv, const float* __restrict__ pw,
    const float* __restrict__ gate_up,
    short* __restrict__ wqkv, short* __restrict__ wproj, short* __restrict__ wgu_t) {
  __shared__ short T[64*66];
  const int bid = blockIdx.x;
  const int t = threadIdx.x;
  if (bid < 2560) {
    const int row = bid;
    const int c = t * 4;
    const float* src; short* dst;
    if (row < 1024)      { src = cq + (size_t)row*NDIM;        dst = wqkv + (size_t)row*NDIM; }
    else if (row < 1280) { src = ck + (size_t)(row-1024)*NDIM; dst = wqkv + (size_t)row*NDIM; }
    else if (row < 1536) { src = cv + (size_t)(row-1280)*NDIM; dst = wqkv + (size_t)row*NDIM; }
    else                 { src = pw + (size_t)(row-1536)*NDIM; dst = wproj + (size_t)(row-1536)*NDIM; }
    float4 v = *(const float4*)(src + c);
    short4v o = {f2b(v.x), f2b(v.y), f2b(v.z), f2b(v.w)};
    *(short4v*)(dst + c) = o;
  } else {
    const int b2 = bid - 2560;
    const int kt = b2 & 15, nt = (b2 >> 4) & 15, e = b2 >> 8;
    const float* ie = gate_up + (size_t)e*1024*1024 + (size_t)(kt*64)*1024 + nt*64;
    short* we = wgu_t + (size_t)e*1024*1024;
    const int r = t >> 4, c = (t & 15) * 4;
#pragma unroll
    for (int p = 0; p < 4; ++p) {
      float4 v = *(const float4*)(ie + (size_t)(p*16 + r)*1024 + c);
      T[(p*16 + r)*66 + c + 0] = f2b(v.x);
      T[(p*16 + r)*66 + c + 1] = f2b(v.y);
      T[(p*16 + r)*66 + c + 2] = f2b(v.z);
      T[(p*16 + r)*66 + c + 3] = f2b(v.w);
    }
    __syncthreads();
#pragma unroll
    for (int p = 0; p < 4; ++p) {
      int rr = p*16 + r;
      int R = nt*64 + rr;            // original gate_up column (0..511 gate, 512..1023 up)
      int Rn = (R < 512) ? ((R & ~15)*2 + (R & 15))
                         : (((R - 512) & ~15)*2 + 16 + (R & 15));
      short4v o = {T[(c+0)*66 + rr], T[(c+1)*66 + rr], T[(c+2)*66 + rr], T[(c+3)*66 + rr]};
      *(short4v*)(we + (size_t)Rn*1024 + kt*64 + c) = o;
    }
  }
}

// ---------------- W1: per-expert transpose fp32 [KIN][NIN] -> bf16 [NIN][KIN] ----------------
__global__ __launch_bounds__(256) void k_w_transpose(
    const float* __restrict__ in, short* __restrict__ outp, int KIN, int NIN) {
  __shared__ short T[64*66];
  const int kt = blockIdx.x, nt = blockIdx.y, e = blockIdx.z;
  const float* ie = in + (size_t)e*KIN*NIN + (size_t)(kt*64)*NIN + nt*64;
  short* oe = outp + (size_t)e*NIN*KIN + (size_t)(nt*64)*KIN + kt*64;
  const int t = threadIdx.x;
  const int r = t >> 4, c = (t & 15) * 4;
#pragma unroll
  for (int p = 0; p < 4; ++p) {
    float4 v = *(const float4*)(ie + (size_t)(p*16 + r)*NIN + c);
    T[(p*16 + r)*66 + c + 0] = f2b(v.x);
    T[(p*16 + r)*66 + c + 1] = f2b(v.y);
    T[(p*16 + r)*66 + c + 2] = f2b(v.z);
    T[(p*16 + r)*66 + c + 3] = f2b(v.w);
  }
  __syncthreads();
#pragma unroll
  for (int p = 0; p < 4; ++p) {
    int rr = p*16 + r;
    short4v o = {T[(c+0)*66 + rr], T[(c+1)*66 + rr], T[(c+2)*66 + rr], T[(c+3)*66 + rr]};
    *(short4v*)(oe + (size_t)rr*KIN + c) = o;
  }
}

// ---------------- K1: xr(bf16) = mix; n(bf16) = rmsnorm ----------------
__global__ __launch_bounds__(256) void k_resid_rms(
    const float* __restrict__ x, const float* __restrict__ x0,
    const float* __restrict__ rmix, short* __restrict__ xr, short* __restrict__ nrm) {
  const int row = blockIdx.x;
  const int t = threadIdx.x;
  const int d = t * 4;
  const size_t base = (size_t)row * NDIM + d;
  float4 a  = *(const float4*)(x  + base);
  float4 b  = *(const float4*)(x0 + base);
  float4 m0 = *(const float4*)(rmix + d);
  float4 m1 = *(const float4*)(rmix + NDIM + d);
  float4 r;
  r.x = m0.x*a.x + m1.x*b.x;
  r.y = m0.y*a.y + m1.y*b.y;
  r.z = m0.z*a.z + m1.z*b.z;
  r.w = m0.w*a.w + m1.w*b.w;
  float ss = r.x*r.x + r.y*r.y + r.z*r.z + r.w*r.w;
  ss = wred64(ss);
  __shared__ float wsum[4];
  if ((t & 63) == 0) wsum[t >> 6] = ss;
  __syncthreads();
  float tot = wsum[0] + wsum[1] + wsum[2] + wsum[3];
  float rms = rsqrtf(tot * (1.0f/NDIM) + RMS_EPS);
  short4v xo = {f2b(r.x), f2b(r.y), f2b(r.z), f2b(r.w)};
  short4v no = {f2b(r.x*rms), f2b(r.y*rms), f2b(r.z*rms), f2b(r.w*rms)};
  *(short4v*)(xr + base) = xo;
  *(short4v*)(nrm + base) = no;
}

// ---------------- K2: MFMA GEMM 128x128, BK=32, 2-phase double-buffered staging ----------------
// MODE 0: plain rows -> bf16. MODE 1: gather-A -> bf16. MODE 2: compact-A -> scatter-add fp32.
// MODE 3: gather-A, interleaved gate/up B -> fused silu, compact bf16 h [slots][512].
template <int MODE>
__global__ __launch_bounds__(256) void k_gemm_mfma(
    const short* __restrict__ A, int lda,
    const short* __restrict__ Bw, int K, int N,
    short* __restrict__ Cb, float* __restrict__ Cf, int ldc,
    const int* __restrict__ rowmap, const int* __restrict__ tiletab,
    const int* __restrict__ meta, const float* __restrict__ mscale) {
  __shared__ short sA[2][128*32];
  __shared__ short sB[2][128*32];
  int row0, end = 0x7fffffff, e = 0;
  if (MODE == 0) {
    row0 = blockIdx.y * 128;
  } else {
    e = tiletab[2*blockIdx.y];
    if (e < 0) return;
    row0 = tiletab[2*blockIdx.y + 1];
    end = meta[1 + e];
  }
  const int t = threadIdx.x;
  const int w = t >> 6, l = t & 63;
  const int wr = (w >> 1) * 64, wc = (w & 1) * 64;
  const int lrow = l & 15, lk8 = (l >> 4) * 8;
  const int srow0 = w*16 + (l >> 2);
  const int scol = (l & 3) * 8;
  const short* Bp = Bw + (size_t)e * N * K + (size_t)(blockIdx.x * 128) * K;
  const short* gA0;
  const short* gA1;
  if (MODE == 1 || MODE == 3) {
    int s0 = row0 + srow0;      if (s0 >= NTOK) s0 = NTOK - 1;
    int s1 = row0 + 64 + srow0; if (s1 >= NTOK) s1 = NTOK - 1;
    gA0 = A + (size_t)rowmap[s0] * lda + scol;
    gA1 = A + (size_t)rowmap[s1] * lda + scol;
  } else {
    gA0 = A + (size_t)(row0 + srow0) * lda + scol;
    gA1 = A + (size_t)(row0 + 64 + srow0) * lda + scol;
  }
  const short* gB0 = Bp + (size_t)srow0 * K + scol;
  const short* gB1 = Bp + (size_t)(64 + srow0) * K + scol;
  const int lo0 = (w*16)*32;          // wave-uniform LDS offsets
  const int lo1 = (64 + w*16)*32;
  f32x4 acc[4][4];
#pragma unroll
  for (int m = 0; m < 4; ++m)
#pragma unroll
    for (int n = 0; n < 4; ++n) acc[m][n] = 0.f;
  // prologue: stage tile 0 into buf 0
  load_lds16(gA0, sA[0] + lo0);
  load_lds16(gA1, sA[0] + lo1);
  load_lds16(gB0, sB[0] + lo0);
  load_lds16(gB1, sB[0] + lo1);
  gA0 += 32; gA1 += 32; gB0 += 32; gB1 += 32;
  int cur = 0;
  for (int k0 = 0; k0 < K; k0 += 32) {
    __syncthreads();                 // drains vmcnt: buf[cur] ready; prior reads of buf[cur^1] done
    if (k0 + 32 < K) {               // prefetch next tile into the other buffer
      load_lds16(gA0, sA[cur^1] + lo0);
      load_lds16(gA1, sA[cur^1] + lo1);
      load_lds16(gB0, sB[cur^1] + lo0);
      load_lds16(gB1, sB[cur^1] + lo1);
      gA0 += 32; gA1 += 32; gB0 += 32; gB1 += 32;
    }
    bf16x8 af[4], bfr[4];
#pragma unroll
    for (int m = 0; m < 4; ++m)
      af[m] = *(const bf16x8*)&sA[cur][(wr + m*16 + lrow)*32 + lk8];
#pragma unroll
    for (int n = 0; n < 4; ++n)
      bfr[n] = *(const bf16x8*)&sB[cur][(wc + n*16 + lrow)*32 + lk8];
    __builtin_amdgcn_s_setprio(1);
#pragma unroll
    for (int m = 0; m < 4; ++m)
#pragma unroll
      for (int n = 0; n < 4; ++n)
        acc[m][n] = __builtin_amdgcn_mfma_f32_16x16x32_bf16(af[m], bfr[n], acc[m][n], 0, 0, 0);
    __builtin_amdgcn_s_setprio(0);
    cur ^= 1;
  }
  const int col0 = blockIdx.x * 128;
  if (MODE <= 1) {
#pragma unroll
    for (int m = 0; m < 4; ++m) {
#pragma unroll
      for (int r = 0; r < 4; ++r) {
        int rr = row0 + wr + m*16 + (l >> 4)*4 + r;
        if (rr < end) {
#pragma unroll
          for (int n = 0; n < 4; ++n)
            Cb[(size_t)rr * ldc + col0 + wc + n*16 + lrow] = f2b(acc[m][n][r]);
        }
      }
    }
  } else if (MODE == 2) {
#pragma unroll
    for (int m = 0; m < 4; ++m) {
#pragma unroll
      for (int r = 0; r < 4; ++r) {
        int slot = row0 + wr + m*16 + (l >> 4)*4 + r;
        if (slot < end) {
          int tok = rowmap[slot];
#pragma unroll
          for (int n = 0; n < 4; ++n) {
            int cc = col0 + wc + n*16 + lrow;
            Cf[(size_t)tok * ldc + cc] += mscale[cc] * acc[m][n][r];
          }
        }
      }
    }
  } else {   // MODE 3: interleaved gate/up pairs -> h = silu(g)*u, compact [slots][512]
    const int fbBase = (col0 + wc) >> 5;
#pragma unroll
    for (int m = 0; m < 4; ++m) {
#pragma unroll
      for (int r = 0; r < 4; ++r) {
        int slot = row0 + wr + m*16 + (l >> 4)*4 + r;
        if (slot < end) {
#pragma unroll
          for (int p = 0; p < 2; ++p) {
            float gg = acc[m][2*p][r], uu = acc[m][2*p+1][r];
            float sg = 1.0f / (1.0f + ex2(-LOG2E * gg));
            Cb[(size_t)slot * NINTER + (fbBase + p)*16 + lrow] = f2b(gg * sg * uu);
          }
        }
      }
    }
  }
}

// --------- K3: per-head rmsnorm + rope (fused V-transpose for bids < 256) ---------
__global__ __launch_bounds__(256) void k_qk_norm_rope(
    short* __restrict__ qkv, const float* __restrict__ q_gain, short* __restrict__ vbT) {
  __shared__ short T[64*72];
  const int row = blockIdx.x;          // b*S+s
  const int t = threadIdx.x;
  const int w = t >> 6, lane = t & 63;
  const int s = row & (NSEQ - 1);
  const int fi = lane & 31;
  const float fr = (float)s * expf(-(float)fi * (LN_10000 / 32.0f));
  const float co = cosf(fr), si = sinf(fr);
#pragma unroll
  for (int h = w; h < NHEAD; h += 4) {
    short* p = qkv + (size_t)row*QKVN + h*HDIM + lane;
    float v = b2f(*p);
    float ssum = wred64(v*v);
    float rr = rsqrtf(ssum * (1.0f/HDIM) + RMS_EPS);
    float vn = v * rr;
    float partner = __shfl_xor(vn, 32);
    float o = (lane < 32) ? (vn*co + partner*si) : (vn*co - partner*si);
    *p = f2b(o * q_gain[h] * QSCALE);
  }
  if (w < NKVH) {
    short* p = qkv + (size_t)row*QKVN + 1024 + w*HDIM + lane;
    float v = b2f(*p);
    float ssum = wred64(v*v);
    float rr = rsqrtf(ssum * (1.0f/HDIM) + RMS_EPS);
    float vn = v * rr;
    float partner = __shfl_xor(vn, 32);
    float o = (lane < 32) ? (vn*co + partner*si) : (vn*co - partner*si);
    *p = f2b(o);
  }
  // blocks 0..255: additionally transpose one V tile (V columns untouched by norm -> no race)
  if (row < 256) {
    const int st = row & 31, kh = (row >> 5) & 3, b = row >> 7;
#pragma unroll
    for (int i = 0; i < 2; ++i) {
      int c = t + i*256;
      int sV = c >> 3, d0 = (c & 7) * 8;
      bf16x8 v = *(const bf16x8*)(qkv + (size_t)(b*NSEQ + st*64 + sV)*QKVN + 1280 + kh*HDIM + d0);
#pragma unroll
      for (int j = 0; j < 8; ++j) T[(d0 + j)*72 + sV] = v[j];
    }
    __syncthreads();
#pragma unroll
    for (int i = 0; i < 2; ++i) {
      int c = t + i*256;
      int d = c >> 3, s0 = (c & 7) * 8;
      *(bf16x8*)(vbT + (size_t)((b*NKVH + kh)*HDIM + d)*NSEQ + st*64 + s0) = *(bf16x8*)&T[d*72 + s0];
    }
  }
}

// ---------------- K4: causal flash attention, swapped-QK^T MFMA, 128-row Q tiles ----------------
// v8 (round-18, proven 52.5us): in-register P (pf = concat of lane-local packed P), V LDS
// key-columns sigma-permuted; balanced qt remap, dbuf reg-staged K/V, defer-max, setprio,
// hoisted K-fragments. No Ps LDS (36.9KB).
__global__ __launch_bounds__(256) void k_attn_mfma(
    const short* __restrict__ qkv, const short* __restrict__ vbT, short* __restrict__ y) {
  __shared__ short Ks[2][64*72];   // [key][dim]
  __shared__ short Vt[2][64*72];   // [dim][key], key-cols sigma-permuted
  const int t = threadIdx.x;
  const int l = t & 63, w = t >> 6;
  const int lrow = l & 15, g = l >> 4, lk8 = g * 8;
  const int bid = blockIdx.x;
  int qt = bid & 15;
  const int h = (bid >> 4) & 15, b = bid >> 8;
  if (b & 1) qt = 15 - qt;   // balance: co-resident pairs sum to constant tile count
  const int kh = h >> 2;
  bf16x8 qf[2][2];   // [qra][k-half]; Q as B-operand (col = q-row)
#pragma unroll
  for (int qra = 0; qra < 2; ++qra) {
    int qrow_g = b*NSEQ + qt*128 + qra*64 + w*16 + lrow;
#pragma unroll
    for (int hf = 0; hf < 2; ++hf)
      qf[qra][hf] = *(const bf16x8*)(qkv + (size_t)qrow_g*QKVN + h*HDIM + hf*32 + lk8);
  }
  const int r0a = t >> 3;
  const int d0a = (t & 7) * 8;
  const int mseg = t & 7;
  // sigma-permuted V column base for this 8-key chunk
  const int vb0 = (mseg >> 2)*32 + (mseg & 1)*16 + ((mseg >> 1) & 1)*4;
  const short* kgbase = qkv + 1024 + (size_t)kh*HDIM;
  const short* vgbase = vbT + (size_t)((b*NKVH + kh)*HDIM)*NSEQ;
  bf16x8 kr0, kr1, vr0, vr1;
#define LOADKV(KT) do { \
    kr0 = *(const bf16x8*)(kgbase + (size_t)(b*NSEQ + (KT)*64 + r0a)*QKVN + d0a); \
    kr1 = *(const bf16x8*)(kgbase + (size_t)(b*NSEQ + (KT)*64 + r0a + 32)*QKVN + d0a); \
    vr0 = *(const bf16x8*)(vgbase + (size_t)r0a*NSEQ + (KT)*64 + d0a); \
    vr1 = *(const bf16x8*)(vgbase + (size_t)(r0a + 32)*NSEQ + (KT)*64 + d0a); \
  } while (0)
  float m_i[2] = {-INFINITY, -INFINITY};
  float l_i[2] = {0.f, 0.f};
  f32x4 O[2][4];
#pragma unroll
  for (int qra = 0; qra < 2; ++qra)
#pragma unroll
    for (int db = 0; db < 4; ++db) O[qra][db] = 0.f;
  const int ktmax = 2*qt + 1;
  LOADKV(0);
  for (int kt = 0; kt <= ktmax; ++kt) {
    const int buf = kt & 1;
    *(bf16x8*)&Ks[buf][r0a*72 + d0a] = kr0;
    *(bf16x8*)&Ks[buf][(r0a + 32)*72 + d0a] = kr1;
    {  // V: sigma-permuted columns -> two b64 writes per 8-key chunk per row
      short4v* v0p = (short4v*)&vr0;
      short4v* v1p = (short4v*)&vr1;
      *(short4v*)&Vt[buf][r0a*72 + vb0]            = v0p[0];
      *(short4v*)&Vt[buf][r0a*72 + vb0 + 8]        = v0p[1];
      *(short4v*)&Vt[buf][(r0a + 32)*72 + vb0]     = v1p[0];
      *(short4v*)&Vt[buf][(r0a + 32)*72 + vb0 + 8] = v1p[1];
    }
    __syncthreads();
    if (kt < ktmax) LOADKV(kt + 1);   // async prefetch: lands during compute below
    // K fragments are qra-invariant: read ONCE per tile
    bf16x8 kf[4][2];
#pragma unroll
    for (int nb = 0; nb < 4; ++nb) {
      kf[nb][0] = *(const bf16x8*)&Ks[buf][(nb*16 + lrow)*72 + lk8];
      kf[nb][1] = *(const bf16x8*)&Ks[buf][(nb*16 + lrow)*72 + 32 + lk8];
    }
    const int qra0 = (kt == ktmax) ? 1 : 0;   // q-rows 0..63 fully masked on last tile
    bf16x8 pf[2][2];
#pragma unroll
    for (int qra = 0; qra < 2; ++qra) {
      if (qra >= qra0) {
        f32x4 sc[4];
#pragma unroll
        for (int nb = 0; nb < 4; ++nb) sc[nb] = 0.f;
        __builtin_amdgcn_s_setprio(1);
#pragma unroll
        for (int nb = 0; nb < 4; ++nb) {
          sc[nb] = __builtin_amdgcn_mfma_f32_16x16x32_bf16(kf[nb][0], qf[qra][0], sc[nb], 0, 0, 0);
          sc[nb] = __builtin_amdgcn_mfma_f32_16x16x32_bf16(kf[nb][1], qf[qra][1], sc[nb], 0, 0, 0);
        }
        __builtin_amdgcn_s_setprio(0);
        if (kt >= 2*qt) {   // diagonal tiles: elementwise causal mask
          int qg = qt*128 + qra*64 + w*16 + lrow;
#pragma unroll
          for (int nb = 0; nb < 4; ++nb)
#pragma unroll
            for (int r = 0; r < 4; ++r)
              if (kt*64 + nb*16 + g*4 + r > qg) sc[nb][r] = -INFINITY;
        }
        float rm = sc[0][0];
#pragma unroll
        for (int nb = 0; nb < 4; ++nb)
#pragma unroll
          for (int r = 0; r < 4; ++r) rm = fmaxf(rm, sc[nb][r]);
        rm = fmaxf(rm, __shfl_xor(rm, 16));
        rm = fmaxf(rm, __shfl_xor(rm, 32));
        if (!__all(rm <= m_i[qra] + DEFER_THR)) {
          float mn = fmaxf(m_i[qra], rm);
          float fac = ex2(m_i[qra] - mn);
          l_i[qra] *= fac;
          m_i[qra] = mn;
#pragma unroll
          for (int r = 0; r < 4; ++r) {
            float ff = __shfl(fac, g*4 + r);
#pragma unroll
            for (int db = 0; db < 4; ++db) O[qra][db][r] *= ff;
          }
        }
        float rs = 0.f;
#pragma unroll
        for (int nb = 0; nb < 4; ++nb) {
#pragma unroll
          for (int r = 0; r < 4; ++r) {
            float p = ex2(sc[nb][r] - m_i[qra]);
            sc[nb][r] = p;
            rs += p;
          }
        }
        rs += __shfl_xor(rs, 16);
        rs += __shfl_xor(rs, 32);
        l_i[qra] += rs;
        // ---- in-register P: pf[H] = concat(pk[2H], pk[2H+1]), fully lane-local ----
        unsigned pk[4][2];
#pragma unroll
        for (int nb = 0; nb < 4; ++nb) {
          asm("v_cvt_pk_bf16_f32 %0, %1, %2" : "=v"(pk[nb][0]) : "v"(sc[nb][0]), "v"(sc[nb][1]));
          asm("v_cvt_pk_bf16_f32 %0, %1, %2" : "=v"(pk[nb][1]) : "v"(sc[nb][2]), "v"(sc[nb][3]));
        }
#pragma unroll
        for (int H = 0; H < 2; ++H) {
          union { unsigned u[4]; bf16x8 v; } P;
          P.u[0] = pk[2*H][0];
          P.u[1] = pk[2*H][1];
          P.u[2] = pk[2*H+1][0];
          P.u[3] = pk[2*H+1][1];
          pf[qra][H] = P.v;
        }
      }
    }
    __builtin_amdgcn_s_setprio(1);
#pragma unroll
    for (int db = 0; db < 4; ++db) {
      bf16x8 vf0 = *(const bf16x8*)&Vt[buf][(db*16 + lrow)*72 + lk8];
      bf16x8 vf1 = *(const bf16x8*)&Vt[buf][(db*16 + lrow)*72 + 32 + lk8];
      if (qra0 == 0) {
        O[0][db] = __builtin_amdgcn_mfma_f32_16x16x32_bf16(pf[0][0], vf0, O[0][db], 0, 0, 0);
        O[0][db] = __builtin_amdgcn_mfma_f32_16x16x32_bf16(pf[0][1], vf1, O[0][db], 0, 0, 0);
      }
      O[1][db] = __builtin_amdgcn_mfma_f32_16x16x32_bf16(pf[1][0], vf0, O[1][db], 0, 0, 0);
      O[1][db] = __builtin_amdgcn_mfma_f32_16x16x32_bf16(pf[1][1], vf1, O[1][db], 0, 0, 0);
    }
    __builtin_amdgcn_s_setprio(0);
  }
#undef LOADKV
#pragma unroll
  for (int qra = 0; qra < 2; ++qra) {
    float linv = 1.0f / l_i[qra];
#pragma unroll
    for (int r = 0; r < 4; ++r) {
      float inv = __shfl(linv, g*4 + r);
      int rowo = b*NSEQ + qt*128 + qra*64 + w*16 + g*4 + r;
#pragma unroll
      for (int db = 0; db < 4; ++db)
        y[(size_t)rowo*NDIM + h*HDIM + db*16 + lrow] = f2b(O[qra][db][r] * inv);
    }
  }
}

// --------- K5: x2/v_next -> out(f32) ; mbuf = rmsnorm(x2) bf16 ; block 0 also routes ---------
__global__ __launch_bounds__(256) void k_fuse_vel(
    const short* __restrict__ xr, const short* __restrict__ aout,
    const float* __restrict__ vel, const float* __restrict__ ascale,
    const float* __restrict__ mu, float* __restrict__ out, short* __restrict__ mbuf,
    const int* __restrict__ eids, int* __restrict__ rowmap,
    int* __restrict__ tiletab, int* __restrict__ meta) {
  const int row = blockIdx.x;
  const int t = threadIdx.x;
  const int d = t * 4;
  const size_t base = (size_t)row * NDIM + d;
  short4v a4 = *(const short4v*)(xr + base);
  short4v o4 = *(const short4v*)(aout + base);
  float4 vv = *(const float4*)(vel + base);
  float4 as = *(const float4*)(ascale + d);
  float4 mu4 = *(const float4*)(mu + d);
  float xs[4], vns[4];
  const float asl[4] = {as.x, as.y, as.z, as.w};
  const float mul[4] = {mu4.x, mu4.y, mu4.z, mu4.w};
  const float vvl[4] = {vv.x, vv.y, vv.z, vv.w};
#pragma unroll
  for (int i = 0; i < 4; ++i) {
    float x1 = b2f(a4[i]) + asl[i] * b2f(o4[i]);
    float muc = fminf(fmaxf(mul[i], 0.5f), 1.5f);
    float vn = fminf(fmaxf(0.95f*vvl[i] - 0.3f*(x1 - muc), -3.f), 3.f);
    xs[i] = x1 + 0.01f*vn;
    vns[i] = vn;
  }
  float4 x2 = {xs[0], xs[1], xs[2], xs[3]};
  float4 vnq = {vns[0], vns[1], vns[2], vns[3]};
  *(float4*)(out + base) = x2;
  *(float4*)(out + (size_t)NTOK*NDIM + base) = vnq;
  float ss = xs[0]*xs[0] + xs[1]*xs[1] + xs[2]*xs[2] + xs[3]*xs[3];
  ss = wred64(ss);
  __shared__ float wsum[4];
  if ((t & 63) == 0) wsum[t >> 6] = ss;
  __syncthreads();
  float tot = wsum[0] + wsum[1] + wsum[2] + wsum[3];
  float rms = rsqrtf(tot * (1.0f/NDIM) + RMS_EPS);
  short4v m4 = {f2b(xs[0]*rms), f2b(xs[1]*rms), f2b(xs[2]*rms), f2b(xs[3]*rms)};
  *(short4v*)(mbuf + base) = m4;
  // ---- block 0: token routing (consumed by gemm1/gemm2, which launch after this kernel) ----
  if (blockIdx.x == 0) {
    __shared__ int cnt[NEXP];
    __shared__ int ctr[NEXP];
    if (t < NEXP) cnt[t] = 0;
    __syncthreads();
    for (int i = t; i < NTOK; i += 256) atomicAdd(&cnt[eids[i]], 1);
    __syncthreads();
    if (t == 0) {
      int off = 0, tile = 0;
      for (int e = 0; e < NEXP; ++e) {
        ctr[e] = off;
        int nt_e = (cnt[e] + 127) >> 7;
        for (int j = 0; j < nt_e; ++j) { tiletab[2*tile] = e; tiletab[2*tile+1] = off + j*128; ++tile; }
        off += cnt[e];
        meta[1 + e] = off;
      }
      meta[0] = tile;
      for (int j = tile; j < MAXTILE; ++j) { tiletab[2*j] = -1; tiletab[2*j+1] = 0; }
    }
    __syncthreads();
    for (int i = t; i < NTOK; i += 256) {
      int e = eids[i];
      int slot = atomicAdd(&ctr[e], 1);
      rowmap[slot] = i;
    }
  }
}

extern "C" void kernel_launch(void* const* d_in, const int* in_sizes, int n_in,
                              void* d_out, int out_size, void* d_ws, size_t ws_size,
                              hipStream_t stream) {
  const float* x      = (const float*)d_in[0];
  const float* x0     = (const float*)d_in[1];
  const float* vel    = (const float*)d_in[2];
  const float* rmix   = (const float*)d_in[3];
  const float* ascale = (const float*)d_in[4];
  const float* mscale = (const float*)d_in[5];
  const float* cq_w   = (const float*)d_in[6];
  const float* ck_w   = (const float*)d_in[7];
  const float* cv_w   = (const float*)d_in[8];
  const float* proj_w = (const float*)d_in[9];
  const float* q_gain = (const float*)d_in[10];
  const float* mu     = (const float*)d_in[11];
  const float* gate_up= (const float*)d_in[12];
  const float* down   = (const float*)d_in[13];
  const int*   eids   = (const int*)d_in[14];
  float* out = (float*)d_out;
  char* base = (char*)d_ws;

  const size_t MB = 1024*1024;
  short* wqkv  = (short*)base;            // [0,3)
  short* wproj = (short*)(base + 3*MB);   // [3,5)
  int*   rowmap  = (int*)(base + 5*MB);   // [5,6)
  int*   tiletab = rowmap + NTOK;
  int*   meta    = tiletab + 2*MAXTILE;
  short* wgu_t = (short*)(base + 6*MB);   // [6,22): interleaved gate/up weights
  short* xr    = (short*)(base + 22*MB);  // [22,30): xr -> hbuf after fuse_vel
  short* hbuf  = xr;
  short* nbuf  = (short*)(base + 30*MB);  // [30,38): n -> y -> mbuf -> wdn_t
  short* ybuf  = nbuf;
  short* mbuf  = nbuf;
  short* wdn_t = nbuf;
  short* qkv   = (short*)(base + 38*MB);  // [38,50): qkv -> aout after attn
  short* aout  = qkv;
  short* vbT   = (short*)(base + 50*MB);  // [50,52)

  k_w_prep<<<4608, 256, 0, stream>>>(cq_w, ck_w, cv_w, proj_w, gate_up, wqkv, wproj, wgu_t);
  k_resid_rms<<<NTOK, 256, 0, stream>>>(x, x0, rmix, xr, nbuf);
  k_gemm_mfma<0><<<dim3(QKVN/128, NTOK/128), 256, 0, stream>>>(
      nbuf, NDIM, wqkv, NDIM, QKVN, qkv, nullptr, QKVN, nullptr, nullptr, nullptr, nullptr);
  k_qk_norm_rope<<<NTOK, 256, 0, stream>>>(qkv, q_gain, vbT);
  k_attn_mfma<<<NBATCH*NHEAD*(NSEQ/128), 256, 0, stream>>>(qkv, vbT, ybuf);
  k_gemm_mfma<0><<<dim3(NDIM/128, NTOK/128), 256, 0, stream>>>(
      ybuf, NDIM, wproj, NDIM, NDIM, aout, nullptr, NDIM, nullptr, nullptr, nullptr, nullptr);
  k_fuse_vel<<<NTOK, 256, 0, stream>>>(xr, aout, vel, ascale, mu, out, mbuf,
                                       eids, rowmap, tiletab, meta);
  k_gemm_mfma<3><<<dim3(1024/128, MAXTILE), 256, 0, stream>>>(
      mbuf, NDIM, wgu_t, NDIM, 1024, hbuf, nullptr, NINTER, rowmap, tiletab, meta, nullptr);
  k_w_transpose<<<dim3(8, 16, 8), 256, 0, stream>>>(down, wdn_t, 512, 1024);
  k_gemm_mfma<2><<<dim3(NDIM/128, MAXTILE), 256, 0, stream>>>(
      hbuf, NINTER, wdn_t, NINTER, NDIM, nullptr, out, NDIM, rowmap, tiletab, meta, mscale);
}

// Round 21
// 208.449 us; speedup vs baseline: 1.5672x; 1.0290x over previous
//
#include <hip/hip_runtime.h>
#include <hip/hip_bf16.h>
#include <math.h>

#define NBATCH 2
#define NSEQ   2048
#define NDIM   1024
#define NHEAD  16
#define NKVH   4
#define HDIM   64
#define KVD    256
#define NEXP   8
#define NINTER 512
#define NTOK   (NBATCH*NSEQ)
#define QKVN   1536
#define MAXTILE 40
#define RMS_EPS 1.1920929e-07f
#define LN_10000 9.210340371976184f
#define QSCALE (0.125f * 1.44269504088896f)   // 1/sqrt(64) * log2(e), folded into Q
#define DEFER_THR 11.5f                        // log2 domain ~= e^8
#define LOG2E 1.44269504088896f

typedef __attribute__((ext_vector_type(8))) short bf16x8;
typedef __attribute__((ext_vector_type(4))) short short4v;
typedef __attribute__((ext_vector_type(4))) float f32x4;

// compiler-cast bf16 conversion: RNE, clang fuses pairs into v_cvt_pk_bf16_f32
__device__ __forceinline__ short f2b(float f) {
  return __builtin_bit_cast(short, (__bf16)f);
}
__device__ __forceinline__ float b2f(short s) {
  unsigned u = ((unsigned)(unsigned short)s) << 16;
  return __builtin_bit_cast(float, u);
}
__device__ __forceinline__ float ex2(float x) {   // 2^x via v_exp_f32
  float r; asm("v_exp_f32 %0, %1" : "=v"(r) : "v"(x)); return r;
}
__device__ __forceinline__ void load_lds16(const short* g, short* l) {
  __builtin_amdgcn_global_load_lds((const __attribute__((address_space(1))) void*)g,
                                   (__attribute__((address_space(3))) void*)l, 16, 0, 0);
}

__device__ __forceinline__ float wred64(float v) {
#pragma unroll
  for (int m = 32; m >= 1; m >>= 1) v += __shfl_xor(v, m);
  return v;
}

// ---- W0: merged prep: cast wqkv/wproj (bids 0..2559) + transpose gate_up interleaved
//      (bids 2560..4607) + resid_rms (bids 4608..8703: xr/n for token bid-4608) ----
__global__ __launch_bounds__(256) void k_w_prep(
    const float* __restrict__ cq, const float* __restrict__ ck,
    const float* __restrict__ cv, const float* __restrict__ pw,
    const float* __restrict__ gate_up,
    short* __restrict__ wqkv, short* __restrict__ wproj, short* __restrict__ wgu_t,
    const float* __restrict__ x, const float* __restrict__ x0,
    const float* __restrict__ rmix, short* __restrict__ xr, short* __restrict__ nrm) {
  __shared__ short T[64*66];
  __shared__ float wsum[4];
  const int bid = blockIdx.x;
  const int t = threadIdx.x;
  if (bid < 2560) {
    const int row = bid;
    const int c = t * 4;
    const float* src; short* dst;
    if (row < 1024)      { src = cq + (size_t)row*NDIM;        dst = wqkv + (size_t)row*NDIM; }
    else if (row < 1280) { src = ck + (size_t)(row-1024)*NDIM; dst = wqkv + (size_t)row*NDIM; }
    else if (row < 1536) { src = cv + (size_t)(row-1280)*NDIM; dst = wqkv + (size_t)row*NDIM; }
    else                 { src = pw + (size_t)(row-1536)*NDIM; dst = wproj + (size_t)(row-1536)*NDIM; }
    float4 v = *(const float4*)(src + c);
    short4v o = {f2b(v.x), f2b(v.y), f2b(v.z), f2b(v.w)};
    *(short4v*)(dst + c) = o;
  } else if (bid < 4608) {
    const int b2 = bid - 2560;
    const int kt = b2 & 15, nt = (b2 >> 4) & 15, e = b2 >> 8;
    const float* ie = gate_up + (size_t)e*1024*1024 + (size_t)(kt*64)*1024 + nt*64;
    short* we = wgu_t + (size_t)e*1024*1024;
    const int r = t >> 4, c = (t & 15) * 4;
#pragma unroll
    for (int p = 0; p < 4; ++p) {
      float4 v = *(const float4*)(ie + (size_t)(p*16 + r)*1024 + c);
      T[(p*16 + r)*66 + c + 0] = f2b(v.x);
      T[(p*16 + r)*66 + c + 1] = f2b(v.y);
      T[(p*16 + r)*66 + c + 2] = f2b(v.z);
      T[(p*16 + r)*66 + c + 3] = f2b(v.w);
    }
    __syncthreads();
#pragma unroll
    for (int p = 0; p < 4; ++p) {
      int rr = p*16 + r;
      int R = nt*64 + rr;            // original gate_up column (0..511 gate, 512..1023 up)
      int Rn = (R < 512) ? ((R & ~15)*2 + (R & 15))
                         : (((R - 512) & ~15)*2 + 16 + (R & 15));
      short4v o = {T[(c+0)*66 + rr], T[(c+1)*66 + rr], T[(c+2)*66 + rr], T[(c+3)*66 + rr]};
      *(short4v*)(we + (size_t)Rn*1024 + kt*64 + c) = o;
    }
  } else {
    // resid_rms for token row = bid - 4608
    const int row = bid - 4608;
    const int d = t * 4;
    const size_t base = (size_t)row * NDIM + d;
    float4 a  = *(const float4*)(x  + base);
    float4 b  = *(const float4*)(x0 + base);
    float4 m0 = *(const float4*)(rmix + d);
    float4 m1 = *(const float4*)(rmix + NDIM + d);
    float4 r;
    r.x = m0.x*a.x + m1.x*b.x;
    r.y = m0.y*a.y + m1.y*b.y;
    r.z = m0.z*a.z + m1.z*b.z;
    r.w = m0.w*a.w + m1.w*b.w;
    float ss = r.x*r.x + r.y*r.y + r.z*r.z + r.w*r.w;
    ss = wred64(ss);
    if ((t & 63) == 0) wsum[t >> 6] = ss;
    __syncthreads();
    float tot = wsum[0] + wsum[1] + wsum[2] + wsum[3];
    float rms = rsqrtf(tot * (1.0f/NDIM) + RMS_EPS);
    short4v xo = {f2b(r.x), f2b(r.y), f2b(r.z), f2b(r.w)};
    short4v no = {f2b(r.x*rms), f2b(r.y*rms), f2b(r.z*rms), f2b(r.w*rms)};
    *(short4v*)(xr + base) = xo;
    *(short4v*)(nrm + base) = no;
  }
}

// ---------------- K2: MFMA GEMM 128x128, BK=32, 2-phase double-buffered staging ----------------
// MODE 0: plain rows -> bf16. MODE 1: gather-A -> bf16. MODE 2: compact-A -> scatter-add fp32.
// MODE 3: gather-A, interleaved gate/up B -> fused silu, compact bf16 h [slots][512].
template <int MODE>
__global__ __launch_bounds__(256) void k_gemm_mfma(
    const short* __restrict__ A, int lda,
    const short* __restrict__ Bw, int K, int N,
    short* __restrict__ Cb, float* __restrict__ Cf, int ldc,
    const int* __restrict__ rowmap, const int* __restrict__ tiletab,
    const int* __restrict__ meta, const float* __restrict__ mscale) {
  __shared__ short sA[2][128*32];
  __shared__ short sB[2][128*32];
  int row0, end = 0x7fffffff, e = 0;
  if (MODE == 0) {
    row0 = blockIdx.y * 128;
  } else {
    e = tiletab[2*blockIdx.y];
    if (e < 0) return;
    row0 = tiletab[2*blockIdx.y + 1];
    end = meta[1 + e];
  }
  const int t = threadIdx.x;
  const int w = t >> 6, l = t & 63;
  const int wr = (w >> 1) * 64, wc = (w & 1) * 64;
  const int lrow = l & 15, lk8 = (l >> 4) * 8;
  const int srow0 = w*16 + (l >> 2);
  const int scol = (l & 3) * 8;
  const short* Bp = Bw + (size_t)e * N * K + (size_t)(blockIdx.x * 128) * K;
  const short* gA0;
  const short* gA1;
  if (MODE == 1 || MODE == 3) {
    int s0 = row0 + srow0;      if (s0 >= NTOK) s0 = NTOK - 1;
    int s1 = row0 + 64 + srow0; if (s1 >= NTOK) s1 = NTOK - 1;
    gA0 = A + (size_t)rowmap[s0] * lda + scol;
    gA1 = A + (size_t)rowmap[s1] * lda + scol;
  } else {
    gA0 = A + (size_t)(row0 + srow0) * lda + scol;
    gA1 = A + (size_t)(row0 + 64 + srow0) * lda + scol;
  }
  const short* gB0 = Bp + (size_t)srow0 * K + scol;
  const short* gB1 = Bp + (size_t)(64 + srow0) * K + scol;
  const int lo0 = (w*16)*32;          // wave-uniform LDS offsets
  const int lo1 = (64 + w*16)*32;
  f32x4 acc[4][4];
#pragma unroll
  for (int m = 0; m < 4; ++m)
#pragma unroll
    for (int n = 0; n < 4; ++n) acc[m][n] = 0.f;
  // prologue: stage tile 0 into buf 0
  load_lds16(gA0, sA[0] + lo0);
  load_lds16(gA1, sA[0] + lo1);
  load_lds16(gB0, sB[0] + lo0);
  load_lds16(gB1, sB[0] + lo1);
  gA0 += 32; gA1 += 32; gB0 += 32; gB1 += 32;
  int cur = 0;
  for (int k0 = 0; k0 < K; k0 += 32) {
    __syncthreads();                 // drains vmcnt: buf[cur] ready; prior reads of buf[cur^1] done
    if (k0 + 32 < K) {               // prefetch next tile into the other buffer
      load_lds16(gA0, sA[cur^1] + lo0);
      load_lds16(gA1, sA[cur^1] + lo1);
      load_lds16(gB0, sB[cur^1] + lo0);
      load_lds16(gB1, sB[cur^1] + lo1);
      gA0 += 32; gA1 += 32; gB0 += 32; gB1 += 32;
    }
    bf16x8 af[4], bfr[4];
#pragma unroll
    for (int m = 0; m < 4; ++m)
      af[m] = *(const bf16x8*)&sA[cur][(wr + m*16 + lrow)*32 + lk8];
#pragma unroll
    for (int n = 0; n < 4; ++n)
      bfr[n] = *(const bf16x8*)&sB[cur][(wc + n*16 + lrow)*32 + lk8];
    __builtin_amdgcn_s_setprio(1);
#pragma unroll
    for (int m = 0; m < 4; ++m)
#pragma unroll
      for (int n = 0; n < 4; ++n)
        acc[m][n] = __builtin_amdgcn_mfma_f32_16x16x32_bf16(af[m], bfr[n], acc[m][n], 0, 0, 0);
    __builtin_amdgcn_s_setprio(0);
    cur ^= 1;
  }
  const int col0 = blockIdx.x * 128;
  if (MODE <= 1) {
#pragma unroll
    for (int m = 0; m < 4; ++m) {
#pragma unroll
      for (int r = 0; r < 4; ++r) {
        int rr = row0 + wr + m*16 + (l >> 4)*4 + r;
        if (rr < end) {
#pragma unroll
          for (int n = 0; n < 4; ++n)
            Cb[(size_t)rr * ldc + col0 + wc + n*16 + lrow] = f2b(acc[m][n][r]);
        }
      }
    }
  } else if (MODE == 2) {
#pragma unroll
    for (int m = 0; m < 4; ++m) {
#pragma unroll
      for (int r = 0; r < 4; ++r) {
        int slot = row0 + wr + m*16 + (l >> 4)*4 + r;
        if (slot < end) {
          int tok = rowmap[slot];
#pragma unroll
          for (int n = 0; n < 4; ++n) {
            int cc = col0 + wc + n*16 + lrow;
            Cf[(size_t)tok * ldc + cc] += mscale[cc] * acc[m][n][r];
          }
        }
      }
    }
  } else {   // MODE 3: interleaved gate/up pairs -> h = silu(g)*u, compact [slots][512]
    const int fbBase = (col0 + wc) >> 5;
#pragma unroll
    for (int m = 0; m < 4; ++m) {
#pragma unroll
      for (int r = 0; r < 4; ++r) {
        int slot = row0 + wr + m*16 + (l >> 4)*4 + r;
        if (slot < end) {
#pragma unroll
          for (int p = 0; p < 2; ++p) {
            float gg = acc[m][2*p][r], uu = acc[m][2*p+1][r];
            float sg = 1.0f / (1.0f + ex2(-LOG2E * gg));
            Cb[(size_t)slot * NINTER + (fbBase + p)*16 + lrow] = f2b(gg * sg * uu);
          }
        }
      }
    }
  }
}

// --------- K3: per-head rmsnorm + rope (fused V-transpose for bids < 256) ---------
__global__ __launch_bounds__(256) void k_qk_norm_rope(
    short* __restrict__ qkv, const float* __restrict__ q_gain, short* __restrict__ vbT) {
  __shared__ short T[64*72];
  const int row = blockIdx.x;          // b*S+s
  const int t = threadIdx.x;
  const int w = t >> 6, lane = t & 63;
  const int s = row & (NSEQ - 1);
  const int fi = lane & 31;
  const float fr = (float)s * expf(-(float)fi * (LN_10000 / 32.0f));
  const float co = cosf(fr), si = sinf(fr);
#pragma unroll
  for (int h = w; h < NHEAD; h += 4) {
    short* p = qkv + (size_t)row*QKVN + h*HDIM + lane;
    float v = b2f(*p);
    float ssum = wred64(v*v);
    float rr = rsqrtf(ssum * (1.0f/HDIM) + RMS_EPS);
    float vn = v * rr;
    float partner = __shfl_xor(vn, 32);
    float o = (lane < 32) ? (vn*co + partner*si) : (vn*co - partner*si);
    *p = f2b(o * q_gain[h] * QSCALE);
  }
  if (w < NKVH) {
    short* p = qkv + (size_t)row*QKVN + 1024 + w*HDIM + lane;
    float v = b2f(*p);
    float ssum = wred64(v*v);
    float rr = rsqrtf(ssum * (1.0f/HDIM) + RMS_EPS);
    float vn = v * rr;
    float partner = __shfl_xor(vn, 32);
    float o = (lane < 32) ? (vn*co + partner*si) : (vn*co - partner*si);
    *p = f2b(o);
  }
  // blocks 0..255: additionally transpose one V tile (V columns untouched by norm -> no race)
  if (row < 256) {
    const int st = row & 31, kh = (row >> 5) & 3, b = row >> 7;
#pragma unroll
    for (int i = 0; i < 2; ++i) {
      int c = t + i*256;
      int sV = c >> 3, d0 = (c & 7) * 8;
      bf16x8 v = *(const bf16x8*)(qkv + (size_t)(b*NSEQ + st*64 + sV)*QKVN + 1280 + kh*HDIM + d0);
#pragma unroll
      for (int j = 0; j < 8; ++j) T[(d0 + j)*72 + sV] = v[j];
    }
    __syncthreads();
#pragma unroll
    for (int i = 0; i < 2; ++i) {
      int c = t + i*256;
      int d = c >> 3, s0 = (c & 7) * 8;
      *(bf16x8*)(vbT + (size_t)((b*NKVH + kh)*HDIM + d)*NSEQ + st*64 + s0) = *(bf16x8*)&T[d*72 + s0];
    }
  }
}

// ---------------- K4: causal flash attention, swapped-QK^T MFMA, 128-row Q tiles ----------------
// v8 (round-18, proven 52.5us): in-register P (pf = concat of lane-local packed P), V LDS
// key-columns sigma-permuted; balanced qt remap, dbuf reg-staged K/V, defer-max, setprio,
// hoisted K-fragments. No Ps LDS (36.9KB).
__global__ __launch_bounds__(256) void k_attn_mfma(
    const short* __restrict__ qkv, const short* __restrict__ vbT, short* __restrict__ y) {
  __shared__ short Ks[2][64*72];   // [key][dim]
  __shared__ short Vt[2][64*72];   // [dim][key], key-cols sigma-permuted
  const int t = threadIdx.x;
  const int l = t & 63, w = t >> 6;
  const int lrow = l & 15, g = l >> 4, lk8 = g * 8;
  const int bid = blockIdx.x;
  int qt = bid & 15;
  const int h = (bid >> 4) & 15, b = bid >> 8;
  if (b & 1) qt = 15 - qt;   // balance: co-resident pairs sum to constant tile count
  const int kh = h >> 2;
  bf16x8 qf[2][2];   // [qra][k-half]; Q as B-operand (col = q-row)
#pragma unroll
  for (int qra = 0; qra < 2; ++qra) {
    int qrow_g = b*NSEQ + qt*128 + qra*64 + w*16 + lrow;
#pragma unroll
    for (int hf = 0; hf < 2; ++hf)
      qf[qra][hf] = *(const bf16x8*)(qkv + (size_t)qrow_g*QKVN + h*HDIM + hf*32 + lk8);
  }
  const int r0a = t >> 3;
  const int d0a = (t & 7) * 8;
  const int mseg = t & 7;
  // sigma-permuted V column base for this 8-key chunk
  const int vb0 = (mseg >> 2)*32 + (mseg & 1)*16 + ((mseg >> 1) & 1)*4;
  const short* kgbase = qkv + 1024 + (size_t)kh*HDIM;
  const short* vgbase = vbT + (size_t)((b*NKVH + kh)*HDIM)*NSEQ;
  bf16x8 kr0, kr1, vr0, vr1;
#define LOADKV(KT) do { \
    kr0 = *(const bf16x8*)(kgbase + (size_t)(b*NSEQ + (KT)*64 + r0a)*QKVN + d0a); \
    kr1 = *(const bf16x8*)(kgbase + (size_t)(b*NSEQ + (KT)*64 + r0a + 32)*QKVN + d0a); \
    vr0 = *(const bf16x8*)(vgbase + (size_t)r0a*NSEQ + (KT)*64 + d0a); \
    vr1 = *(const bf16x8*)(vgbase + (size_t)(r0a + 32)*NSEQ + (KT)*64 + d0a); \
  } while (0)
  float m_i[2] = {-INFINITY, -INFINITY};
  float l_i[2] = {0.f, 0.f};
  f32x4 O[2][4];
#pragma unroll
  for (int qra = 0; qra < 2; ++qra)
#pragma unroll
    for (int db = 0; db < 4; ++db) O[qra][db] = 0.f;
  const int ktmax = 2*qt + 1;
  LOADKV(0);
  for (int kt = 0; kt <= ktmax; ++kt) {
    const int buf = kt & 1;
    *(bf16x8*)&Ks[buf][r0a*72 + d0a] = kr0;
    *(bf16x8*)&Ks[buf][(r0a + 32)*72 + d0a] = kr1;
    {  // V: sigma-permuted columns -> two b64 writes per 8-key chunk per row
      short4v* v0p = (short4v*)&vr0;
      short4v* v1p = (short4v*)&vr1;
      *(short4v*)&Vt[buf][r0a*72 + vb0]            = v0p[0];
      *(short4v*)&Vt[buf][r0a*72 + vb0 + 8]        = v0p[1];
      *(short4v*)&Vt[buf][(r0a + 32)*72 + vb0]     = v1p[0];
      *(short4v*)&Vt[buf][(r0a + 32)*72 + vb0 + 8] = v1p[1];
    }
    __syncthreads();
    if (kt < ktmax) LOADKV(kt + 1);   // async prefetch: lands during compute below
    // K fragments are qra-invariant: read ONCE per tile
    bf16x8 kf[4][2];
#pragma unroll
    for (int nb = 0; nb < 4; ++nb) {
      kf[nb][0] = *(const bf16x8*)&Ks[buf][(nb*16 + lrow)*72 + lk8];
      kf[nb][1] = *(const bf16x8*)&Ks[buf][(nb*16 + lrow)*72 + 32 + lk8];
    }
    const int qra0 = (kt == ktmax) ? 1 : 0;   // q-rows 0..63 fully masked on last tile
    bf16x8 pf[2][2];
#pragma unroll
    for (int qra = 0; qra < 2; ++qra) {
      if (qra >= qra0) {
        f32x4 sc[4];
#pragma unroll
        for (int nb = 0; nb < 4; ++nb) sc[nb] = 0.f;
        __builtin_amdgcn_s_setprio(1);
#pragma unroll
        for (int nb = 0; nb < 4; ++nb) {
          sc[nb] = __builtin_amdgcn_mfma_f32_16x16x32_bf16(kf[nb][0], qf[qra][0], sc[nb], 0, 0, 0);
          sc[nb] = __builtin_amdgcn_mfma_f32_16x16x32_bf16(kf[nb][1], qf[qra][1], sc[nb], 0, 0, 0);
        }
        __builtin_amdgcn_s_setprio(0);
        if (kt >= 2*qt) {   // diagonal tiles: elementwise causal mask
          int qg = qt*128 + qra*64 + w*16 + lrow;
#pragma unroll
          for (int nb = 0; nb < 4; ++nb)
#pragma unroll
            for (int r = 0; r < 4; ++r)
              if (kt*64 + nb*16 + g*4 + r > qg) sc[nb][r] = -INFINITY;
        }
        float rm = sc[0][0];
#pragma unroll
        for (int nb = 0; nb < 4; ++nb)
#pragma unroll
          for (int r = 0; r < 4; ++r) rm = fmaxf(rm, sc[nb][r]);
        rm = fmaxf(rm, __shfl_xor(rm, 16));
        rm = fmaxf(rm, __shfl_xor(rm, 32));
        if (!__all(rm <= m_i[qra] + DEFER_THR)) {
          float mn = fmaxf(m_i[qra], rm);
          float fac = ex2(m_i[qra] - mn);
          l_i[qra] *= fac;
          m_i[qra] = mn;
#pragma unroll
          for (int r = 0; r < 4; ++r) {
            float ff = __shfl(fac, g*4 + r);
#pragma unroll
            for (int db = 0; db < 4; ++db) O[qra][db][r] *= ff;
          }
        }
        float rs = 0.f;
#pragma unroll
        for (int nb = 0; nb < 4; ++nb) {
#pragma unroll
          for (int r = 0; r < 4; ++r) {
            float p = ex2(sc[nb][r] - m_i[qra]);
            sc[nb][r] = p;
            rs += p;
          }
        }
        rs += __shfl_xor(rs, 16);
        rs += __shfl_xor(rs, 32);
        l_i[qra] += rs;
        // ---- in-register P: pf[H] = concat(pk[2H], pk[2H+1]), fully lane-local ----
        unsigned pk[4][2];
#pragma unroll
        for (int nb = 0; nb < 4; ++nb) {
          asm("v_cvt_pk_bf16_f32 %0, %1, %2" : "=v"(pk[nb][0]) : "v"(sc[nb][0]), "v"(sc[nb][1]));
          asm("v_cvt_pk_bf16_f32 %0, %1, %2" : "=v"(pk[nb][1]) : "v"(sc[nb][2]), "v"(sc[nb][3]));
        }
#pragma unroll
        for (int H = 0; H < 2; ++H) {
          union { unsigned u[4]; bf16x8 v; } P;
          P.u[0] = pk[2*H][0];
          P.u[1] = pk[2*H][1];
          P.u[2] = pk[2*H+1][0];
          P.u[3] = pk[2*H+1][1];
          pf[qra][H] = P.v;
        }
      }
    }
    __builtin_amdgcn_s_setprio(1);
#pragma unroll
    for (int db = 0; db < 4; ++db) {
      bf16x8 vf0 = *(const bf16x8*)&Vt[buf][(db*16 + lrow)*72 + lk8];
      bf16x8 vf1 = *(const bf16x8*)&Vt[buf][(db*16 + lrow)*72 + 32 + lk8];
      if (qra0 == 0) {
        O[0][db] = __builtin_amdgcn_mfma_f32_16x16x32_bf16(pf[0][0], vf0, O[0][db], 0, 0, 0);
        O[0][db] = __builtin_amdgcn_mfma_f32_16x16x32_bf16(pf[0][1], vf1, O[0][db], 0, 0, 0);
      }
      O[1][db] = __builtin_amdgcn_mfma_f32_16x16x32_bf16(pf[1][0], vf0, O[1][db], 0, 0, 0);
      O[1][db] = __builtin_amdgcn_mfma_f32_16x16x32_bf16(pf[1][1], vf1, O[1][db], 0, 0, 0);
    }
    __builtin_amdgcn_s_setprio(0);
  }
#undef LOADKV
#pragma unroll
  for (int qra = 0; qra < 2; ++qra) {
    float linv = 1.0f / l_i[qra];
#pragma unroll
    for (int r = 0; r < 4; ++r) {
      float inv = __shfl(linv, g*4 + r);
      int rowo = b*NSEQ + qt*128 + qra*64 + w*16 + g*4 + r;
#pragma unroll
      for (int db = 0; db < 4; ++db)
        y[(size_t)rowo*NDIM + h*HDIM + db*16 + lrow] = f2b(O[qra][db][r] * inv);
    }
  }
}

// --------- K5: x2/v_next -> out(f32) ; mbuf = rmsnorm(x2) bf16 ; block 0 also routes ;
//             bids 4096..5119: transpose down fp32 [512][1024] -> wdn_t bf16 [1024][512] ---------
__global__ __launch_bounds__(256) void k_fuse_vel(
    const short* __restrict__ xr, const short* __restrict__ aout,
    const float* __restrict__ vel, const float* __restrict__ ascale,
    const float* __restrict__ mu, float* __restrict__ out, short* __restrict__ mbuf,
    const int* __restrict__ eids, int* __restrict__ rowmap,
    int* __restrict__ tiletab, int* __restrict__ meta,
    const float* __restrict__ down, short* __restrict__ wdn_t) {
  __shared__ short T[64*66];
  __shared__ float wsum[4];
  __shared__ int cnt[NEXP];
  __shared__ int ctr[NEXP];
  const int t = threadIdx.x;
  if (blockIdx.x >= NTOK) {
    // down-transpose tile: KIN=512, NIN=1024
    const int b2 = blockIdx.x - NTOK;
    const int kt = b2 & 7, nt = (b2 >> 3) & 15, e = b2 >> 7;
    const float* ie = down + (size_t)e*512*1024 + (size_t)(kt*64)*1024 + nt*64;
    short* oe = wdn_t + (size_t)e*1024*512 + (size_t)(nt*64)*512 + kt*64;
    const int r = t >> 4, c = (t & 15) * 4;
#pragma unroll
    for (int p = 0; p < 4; ++p) {
      float4 v = *(const float4*)(ie + (size_t)(p*16 + r)*1024 + c);
      T[(p*16 + r)*66 + c + 0] = f2b(v.x);
      T[(p*16 + r)*66 + c + 1] = f2b(v.y);
      T[(p*16 + r)*66 + c + 2] = f2b(v.z);
      T[(p*16 + r)*66 + c + 3] = f2b(v.w);
    }
    __syncthreads();
#pragma unroll
    for (int p = 0; p < 4; ++p) {
      int rr = p*16 + r;
      short4v o = {T[(c+0)*66 + rr], T[(c+1)*66 + rr], T[(c+2)*66 + rr], T[(c+3)*66 + rr]};
      *(short4v*)(oe + (size_t)rr*512 + c) = o;
    }
    return;
  }
  const int row = blockIdx.x;
  const int d = t * 4;
  const size_t base = (size_t)row * NDIM + d;
  short4v a4 = *(const short4v*)(xr + base);
  short4v o4 = *(const short4v*)(aout + base);
  float4 vv = *(const float4*)(vel + base);
  float4 as = *(const float4*)(ascale + d);
  float4 mu4 = *(const float4*)(mu + d);
  float xs[4], vns[4];
  const float asl[4] = {as.x, as.y, as.z, as.w};
  const float mul[4] = {mu4.x, mu4.y, mu4.z, mu4.w};
  const float vvl[4] = {vv.x, vv.y, vv.z, vv.w};
#pragma unroll
  for (int i = 0; i < 4; ++i) {
    float x1 = b2f(a4[i]) + asl[i] * b2f(o4[i]);
    float muc = fminf(fmaxf(mul[i], 0.5f), 1.5f);
    float vn = fminf(fmaxf(0.95f*vvl[i] - 0.3f*(x1 - muc), -3.f), 3.f);
    xs[i] = x1 + 0.01f*vn;
    vns[i] = vn;
  }
  float4 x2 = {xs[0], xs[1], xs[2], xs[3]};
  float4 vnq = {vns[0], vns[1], vns[2], vns[3]};
  *(float4*)(out + base) = x2;
  *(float4*)(out + (size_t)NTOK*NDIM + base) = vnq;
  float ss = xs[0]*xs[0] + xs[1]*xs[1] + xs[2]*xs[2] + xs[3]*xs[3];
  ss = wred64(ss);
  if ((t & 63) == 0) wsum[t >> 6] = ss;
  __syncthreads();
  float tot = wsum[0] + wsum[1] + wsum[2] + wsum[3];
  float rms = rsqrtf(tot * (1.0f/NDIM) + RMS_EPS);
  short4v m4 = {f2b(xs[0]*rms), f2b(xs[1]*rms), f2b(xs[2]*rms), f2b(xs[3]*rms)};
  *(short4v*)(mbuf + base) = m4;
  // ---- block 0: token routing (consumed by gemm1/gemm2, which launch after this kernel) ----
  if (blockIdx.x == 0) {
    if (t < NEXP) cnt[t] = 0;
    __syncthreads();
    for (int i = t; i < NTOK; i += 256) atomicAdd(&cnt[eids[i]], 1);
    __syncthreads();
    if (t == 0) {
      int off = 0, tile = 0;
      for (int e = 0; e < NEXP; ++e) {
        ctr[e] = off;
        int nt_e = (cnt[e] + 127) >> 7;
        for (int j = 0; j < nt_e; ++j) { tiletab[2*tile] = e; tiletab[2*tile+1] = off + j*128; ++tile; }
        off += cnt[e];
        meta[1 + e] = off;
      }
      meta[0] = tile;
      for (int j = tile; j < MAXTILE; ++j) { tiletab[2*j] = -1; tiletab[2*j+1] = 0; }
    }
    __syncthreads();
    for (int i = t; i < NTOK; i += 256) {
      int e = eids[i];
      int slot = atomicAdd(&ctr[e], 1);
      rowmap[slot] = i;
    }
  }
}

extern "C" void kernel_launch(void* const* d_in, const int* in_sizes, int n_in,
                              void* d_out, int out_size, void* d_ws, size_t ws_size,
                              hipStream_t stream) {
  const float* x      = (const float*)d_in[0];
  const float* x0     = (const float*)d_in[1];
  const float* vel    = (const float*)d_in[2];
  const float* rmix   = (const float*)d_in[3];
  const float* ascale = (const float*)d_in[4];
  const float* mscale = (const float*)d_in[5];
  const float* cq_w   = (const float*)d_in[6];
  const float* ck_w   = (const float*)d_in[7];
  const float* cv_w   = (const float*)d_in[8];
  const float* proj_w = (const float*)d_in[9];
  const float* q_gain = (const float*)d_in[10];
  const float* mu     = (const float*)d_in[11];
  const float* gate_up= (const float*)d_in[12];
  const float* down   = (const float*)d_in[13];
  const int*   eids   = (const int*)d_in[14];
  float* out = (float*)d_out;
  char* base = (char*)d_ws;

  const size_t MB = 1024*1024;
  short* wqkv  = (short*)base;            // [0,3)
  short* wproj = (short*)(base + 3*MB);   // [3,5)
  int*   rowmap  = (int*)(base + 5*MB);   // [5,6)
  int*   tiletab = rowmap + NTOK;
  int*   meta    = tiletab + 2*MAXTILE;
  short* wgu_t = (short*)(base + 6*MB);   // [6,22): interleaved gate/up weights
  short* xr    = (short*)(base + 22*MB);  // [22,30): xr -> hbuf after fuse_vel
  short* hbuf  = xr;
  short* nbuf  = (short*)(base + 30*MB);  // [30,38): n -> y -> mbuf
  short* ybuf  = nbuf;
  short* mbuf  = nbuf;
  short* qkv   = (short*)(base + 38*MB);  // [38,50): qkv -> aout after attn
  short* aout  = qkv;
  short* vbT   = (short*)(base + 50*MB);  // [50,52)
  short* wdn_t = (short*)(base + 46*MB);  // [46,54): dead qkv-tail/vbT after attn (ws>=56MB)

  k_w_prep<<<8704, 256, 0, stream>>>(cq_w, ck_w, cv_w, proj_w, gate_up,
                                     wqkv, wproj, wgu_t, x, x0, rmix, xr, nbuf);
  k_gemm_mfma<0><<<dim3(QKVN/128, NTOK/128), 256, 0, stream>>>(
      nbuf, NDIM, wqkv, NDIM, QKVN, qkv, nullptr, QKVN, nullptr, nullptr, nullptr, nullptr);
  k_qk_norm_rope<<<NTOK, 256, 0, stream>>>(qkv, q_gain, vbT);
  k_attn_mfma<<<NBATCH*NHEAD*(NSEQ/128), 256, 0, stream>>>(qkv, vbT, ybuf);
  k_gemm_mfma<0><<<dim3(NDIM/128, NTOK/128), 256, 0, stream>>>(
      ybuf, NDIM, wproj, NDIM, NDIM, aout, nullptr, NDIM, nullptr, nullptr, nullptr, nullptr);
  k_fuse_vel<<<NTOK + 1024, 256, 0, stream>>>(xr, aout, vel, ascale, mu, out, mbuf,
                                              eids, rowmap, tiletab, meta, down, wdn_t);
  k_gemm_mfma<3><<<dim3(1024/128, MAXTILE), 256, 0, stream>>>(
      mbuf, NDIM, wgu_t, NDIM, 1024, hbuf, nullptr, NINTER, rowmap, tiletab, meta, nullptr);
  k_gemm_mfma<2><<<dim3(NDIM/128, MAXTILE), 256, 0, stream>>>(
      hbuf, NINTER, wdn_t, NINTER, NDIM, nullptr, out, NDIM, rowmap, tiletab, meta, mscale);
}

// Round 22
// 205.352 us; speedup vs baseline: 1.5909x; 1.0151x over previous
//
#include <hip/hip_runtime.h>
#include <hip/hip_bf16.h>
#include <math.h>

#define NBATCH 2
#define NSEQ   2048
#define NDIM   1024
#define NHEAD  16
#define NKVH   4
#define HDIM   64
#define KVD    256
#define NEXP   8
#define NINTER 512
#define NTOK   (NBATCH*NSEQ)
#define QKVN   1536
#define MAXTILE 40
#define RMS_EPS 1.1920929e-07f
#define LN_10000 9.210340371976184f
#define QSCALE (0.125f * 1.44269504088896f)   // 1/sqrt(64) * log2(e), folded into Q
#define DEFER_THR 11.5f                        // log2 domain ~= e^8
#define LOG2E 1.44269504088896f

typedef __attribute__((ext_vector_type(8))) short bf16x8;
typedef __attribute__((ext_vector_type(4))) short short4v;
typedef __attribute__((ext_vector_type(4))) float f32x4;

// compiler-cast bf16 conversion: RNE, clang fuses pairs into v_cvt_pk_bf16_f32
__device__ __forceinline__ short f2b(float f) {
  return __builtin_bit_cast(short, (__bf16)f);
}
__device__ __forceinline__ float b2f(short s) {
  unsigned u = ((unsigned)(unsigned short)s) << 16;
  return __builtin_bit_cast(float, u);
}
__device__ __forceinline__ float ex2(float x) {   // 2^x via v_exp_f32
  float r; asm("v_exp_f32 %0, %1" : "=v"(r) : "v"(x)); return r;
}
__device__ __forceinline__ void load_lds16(const short* g, short* l) {
  __builtin_amdgcn_global_load_lds((const __attribute__((address_space(1))) void*)g,
                                   (__attribute__((address_space(3))) void*)l, 16, 0, 0);
}

__device__ __forceinline__ float wred64(float v) {
#pragma unroll
  for (int m = 32; m >= 1; m >>= 1) v += __shfl_xor(v, m);
  return v;
}

// ---- W0: merged prep: cast wqkv/wproj (bids 0..2559) + transpose gate_up interleaved
//      (bids 2560..4607) + resid_rms (bids 4608..8703: xr/n for token bid-4608) ----
__global__ __launch_bounds__(256) void k_w_prep(
    const float* __restrict__ cq, const float* __restrict__ ck,
    const float* __restrict__ cv, const float* __restrict__ pw,
    const float* __restrict__ gate_up,
    short* __restrict__ wqkv, short* __restrict__ wproj, short* __restrict__ wgu_t,
    const float* __restrict__ x, const float* __restrict__ x0,
    const float* __restrict__ rmix, short* __restrict__ xr, short* __restrict__ nrm) {
  __shared__ short T[64*66];
  __shared__ float wsum[4];
  const int bid = blockIdx.x;
  const int t = threadIdx.x;
  if (bid < 2560) {
    const int row = bid;
    const int c = t * 4;
    const float* src; short* dst;
    if (row < 1024)      { src = cq + (size_t)row*NDIM;        dst = wqkv + (size_t)row*NDIM; }
    else if (row < 1280) { src = ck + (size_t)(row-1024)*NDIM; dst = wqkv + (size_t)row*NDIM; }
    else if (row < 1536) { src = cv + (size_t)(row-1280)*NDIM; dst = wqkv + (size_t)row*NDIM; }
    else                 { src = pw + (size_t)(row-1536)*NDIM; dst = wproj + (size_t)(row-1536)*NDIM; }
    float4 v = *(const float4*)(src + c);
    short4v o = {f2b(v.x), f2b(v.y), f2b(v.z), f2b(v.w)};
    *(short4v*)(dst + c) = o;
  } else if (bid < 4608) {
    const int b2 = bid - 2560;
    const int kt = b2 & 15, nt = (b2 >> 4) & 15, e = b2 >> 8;
    const float* ie = gate_up + (size_t)e*1024*1024 + (size_t)(kt*64)*1024 + nt*64;
    short* we = wgu_t + (size_t)e*1024*1024;
    const int r = t >> 4, c = (t & 15) * 4;
#pragma unroll
    for (int p = 0; p < 4; ++p) {
      float4 v = *(const float4*)(ie + (size_t)(p*16 + r)*1024 + c);
      T[(p*16 + r)*66 + c + 0] = f2b(v.x);
      T[(p*16 + r)*66 + c + 1] = f2b(v.y);
      T[(p*16 + r)*66 + c + 2] = f2b(v.z);
      T[(p*16 + r)*66 + c + 3] = f2b(v.w);
    }
    __syncthreads();
#pragma unroll
    for (int p = 0; p < 4; ++p) {
      int rr = p*16 + r;
      int R = nt*64 + rr;            // original gate_up column (0..511 gate, 512..1023 up)
      int Rn = (R < 512) ? ((R & ~15)*2 + (R & 15))
                         : (((R - 512) & ~15)*2 + 16 + (R & 15));
      short4v o = {T[(c+0)*66 + rr], T[(c+1)*66 + rr], T[(c+2)*66 + rr], T[(c+3)*66 + rr]};
      *(short4v*)(we + (size_t)Rn*1024 + kt*64 + c) = o;
    }
  } else {
    // resid_rms for token row = bid - 4608
    const int row = bid - 4608;
    const int d = t * 4;
    const size_t base = (size_t)row * NDIM + d;
    float4 a  = *(const float4*)(x  + base);
    float4 b  = *(const float4*)(x0 + base);
    float4 m0 = *(const float4*)(rmix + d);
    float4 m1 = *(const float4*)(rmix + NDIM + d);
    float4 r;
    r.x = m0.x*a.x + m1.x*b.x;
    r.y = m0.y*a.y + m1.y*b.y;
    r.z = m0.z*a.z + m1.z*b.z;
    r.w = m0.w*a.w + m1.w*b.w;
    float ss = r.x*r.x + r.y*r.y + r.z*r.z + r.w*r.w;
    ss = wred64(ss);
    if ((t & 63) == 0) wsum[t >> 6] = ss;
    __syncthreads();
    float tot = wsum[0] + wsum[1] + wsum[2] + wsum[3];
    float rms = rsqrtf(tot * (1.0f/NDIM) + RMS_EPS);
    short4v xo = {f2b(r.x), f2b(r.y), f2b(r.z), f2b(r.w)};
    short4v no = {f2b(r.x*rms), f2b(r.y*rms), f2b(r.z*rms), f2b(r.w*rms)};
    *(short4v*)(xr + base) = xo;
    *(short4v*)(nrm + base) = no;
  }
}

// ---------------- K2: MFMA GEMM 128x128, BK=32, 2-phase double-buffered staging ----------------
// MODE 0: plain rows -> bf16. MODE 1: gather-A -> bf16. MODE 2: compact-A -> scatter-add fp32.
// MODE 3: gather-A, interleaved gate/up B -> fused silu, compact bf16 h [slots][512].
template <int MODE>
__global__ __launch_bounds__(256) void k_gemm_mfma(
    const short* __restrict__ A, int lda,
    const short* __restrict__ Bw, int K, int N,
    short* __restrict__ Cb, float* __restrict__ Cf, int ldc,
    const int* __restrict__ rowmap, const int* __restrict__ tiletab,
    const int* __restrict__ meta, const float* __restrict__ mscale) {
  __shared__ short sA[2][128*32];
  __shared__ short sB[2][128*32];
  int row0, end = 0x7fffffff, e = 0;
  if (MODE == 0) {
    row0 = blockIdx.y * 128;
  } else {
    e = tiletab[2*blockIdx.y];
    if (e < 0) return;
    row0 = tiletab[2*blockIdx.y + 1];
    end = meta[1 + e];
  }
  const int t = threadIdx.x;
  const int w = t >> 6, l = t & 63;
  const int wr = (w >> 1) * 64, wc = (w & 1) * 64;
  const int lrow = l & 15, lk8 = (l >> 4) * 8;
  const int srow0 = w*16 + (l >> 2);
  const int scol = (l & 3) * 8;
  const short* Bp = Bw + (size_t)e * N * K + (size_t)(blockIdx.x * 128) * K;
  const short* gA0;
  const short* gA1;
  if (MODE == 1 || MODE == 3) {
    int s0 = row0 + srow0;      if (s0 >= NTOK) s0 = NTOK - 1;
    int s1 = row0 + 64 + srow0; if (s1 >= NTOK) s1 = NTOK - 1;
    gA0 = A + (size_t)rowmap[s0] * lda + scol;
    gA1 = A + (size_t)rowmap[s1] * lda + scol;
  } else {
    gA0 = A + (size_t)(row0 + srow0) * lda + scol;
    gA1 = A + (size_t)(row0 + 64 + srow0) * lda + scol;
  }
  const short* gB0 = Bp + (size_t)srow0 * K + scol;
  const short* gB1 = Bp + (size_t)(64 + srow0) * K + scol;
  const int lo0 = (w*16)*32;          // wave-uniform LDS offsets
  const int lo1 = (64 + w*16)*32;
  f32x4 acc[4][4];
#pragma unroll
  for (int m = 0; m < 4; ++m)
#pragma unroll
    for (int n = 0; n < 4; ++n) acc[m][n] = 0.f;
  // prologue: stage tile 0 into buf 0
  load_lds16(gA0, sA[0] + lo0);
  load_lds16(gA1, sA[0] + lo1);
  load_lds16(gB0, sB[0] + lo0);
  load_lds16(gB1, sB[0] + lo1);
  gA0 += 32; gA1 += 32; gB0 += 32; gB1 += 32;
  int cur = 0;
  for (int k0 = 0; k0 < K; k0 += 32) {
    __syncthreads();                 // drains vmcnt: buf[cur] ready; prior reads of buf[cur^1] done
    if (k0 + 32 < K) {               // prefetch next tile into the other buffer
      load_lds16(gA0, sA[cur^1] + lo0);
      load_lds16(gA1, sA[cur^1] + lo1);
      load_lds16(gB0, sB[cur^1] + lo0);
      load_lds16(gB1, sB[cur^1] + lo1);
      gA0 += 32; gA1 += 32; gB0 += 32; gB1 += 32;
    }
    bf16x8 af[4], bfr[4];
#pragma unroll
    for (int m = 0; m < 4; ++m)
      af[m] = *(const bf16x8*)&sA[cur][(wr + m*16 + lrow)*32 + lk8];
#pragma unroll
    for (int n = 0; n < 4; ++n)
      bfr[n] = *(const bf16x8*)&sB[cur][(wc + n*16 + lrow)*32 + lk8];
    __builtin_amdgcn_s_setprio(1);
#pragma unroll
    for (int m = 0; m < 4; ++m)
#pragma unroll
      for (int n = 0; n < 4; ++n)
        acc[m][n] = __builtin_amdgcn_mfma_f32_16x16x32_bf16(af[m], bfr[n], acc[m][n], 0, 0, 0);
    __builtin_amdgcn_s_setprio(0);
    cur ^= 1;
  }
  const int col0 = blockIdx.x * 128;
  if (MODE <= 1) {
#pragma unroll
    for (int m = 0; m < 4; ++m) {
#pragma unroll
      for (int r = 0; r < 4; ++r) {
        int rr = row0 + wr + m*16 + (l >> 4)*4 + r;
        if (rr < end) {
#pragma unroll
          for (int n = 0; n < 4; ++n)
            Cb[(size_t)rr * ldc + col0 + wc + n*16 + lrow] = f2b(acc[m][n][r]);
        }
      }
    }
  } else if (MODE == 2) {
#pragma unroll
    for (int m = 0; m < 4; ++m) {
#pragma unroll
      for (int r = 0; r < 4; ++r) {
        int slot = row0 + wr + m*16 + (l >> 4)*4 + r;
        if (slot < end) {
          int tok = rowmap[slot];
#pragma unroll
          for (int n = 0; n < 4; ++n) {
            int cc = col0 + wc + n*16 + lrow;
            Cf[(size_t)tok * ldc + cc] += mscale[cc] * acc[m][n][r];
          }
        }
      }
    }
  } else {   // MODE 3: interleaved gate/up pairs -> h = silu(g)*u, compact [slots][512]
    const int fbBase = (col0 + wc) >> 5;
#pragma unroll
    for (int m = 0; m < 4; ++m) {
#pragma unroll
      for (int r = 0; r < 4; ++r) {
        int slot = row0 + wr + m*16 + (l >> 4)*4 + r;
        if (slot < end) {
#pragma unroll
          for (int p = 0; p < 2; ++p) {
            float gg = acc[m][2*p][r], uu = acc[m][2*p+1][r];
            float sg = 1.0f / (1.0f + ex2(-LOG2E * gg));
            Cb[(size_t)slot * NINTER + (fbBase + p)*16 + lrow] = f2b(gg * sg * uu);
          }
        }
      }
    }
  }
}

// --------- K3: K-head rmsnorm + rope (Q handled in attn prologue) + V-transpose (bids<256) ---------
__global__ __launch_bounds__(256) void k_k_norm_rope(
    short* __restrict__ qkv, short* __restrict__ vbT) {
  __shared__ short T[64*72];
  const int row = blockIdx.x;          // b*S+s
  const int t = threadIdx.x;
  const int w = t >> 6, lane = t & 63;
  const int s = row & (NSEQ - 1);
  const int fi = lane & 31;
  const float fr = (float)s * expf(-(float)fi * (LN_10000 / 32.0f));
  const float co = cosf(fr), si = sinf(fr);
  if (w < NKVH) {
    short* p = qkv + (size_t)row*QKVN + 1024 + w*HDIM + lane;
    float v = b2f(*p);
    float ssum = wred64(v*v);
    float rr = rsqrtf(ssum * (1.0f/HDIM) + RMS_EPS);
    float vn = v * rr;
    float partner = __shfl_xor(vn, 32);
    float o = (lane < 32) ? (vn*co + partner*si) : (vn*co - partner*si);
    *p = f2b(o);
  }
  // blocks 0..255: additionally transpose one V tile (V columns untouched by norm -> no race)
  if (row < 256) {
    const int st = row & 31, kh = (row >> 5) & 3, b = row >> 7;
#pragma unroll
    for (int i = 0; i < 2; ++i) {
      int c = t + i*256;
      int sV = c >> 3, d0 = (c & 7) * 8;
      bf16x8 v = *(const bf16x8*)(qkv + (size_t)(b*NSEQ + st*64 + sV)*QKVN + 1280 + kh*HDIM + d0);
#pragma unroll
      for (int j = 0; j < 8; ++j) T[(d0 + j)*72 + sV] = v[j];
    }
    __syncthreads();
#pragma unroll
    for (int i = 0; i < 2; ++i) {
      int c = t + i*256;
      int d = c >> 3, s0 = (c & 7) * 8;
      *(bf16x8*)(vbT + (size_t)((b*NKVH + kh)*HDIM + d)*NSEQ + st*64 + s0) = *(bf16x8*)&T[d*72 + s0];
    }
  }
}

// ---------------- K4: causal flash attention, swapped-QK^T MFMA, 128-row Q tiles ----------------
// v9: v8 + Q rmsnorm/rope/gain computed IN the prologue (Q stored raw by the QKV GEMM).
//     Fragment layout makes it lane-local: elem j of qf[qra][hf] is dim hf*32+g*8+j of row
//     w*16+lrow; rope partner (d,d+32) is in-lane across hf; row ss needs shfl_xor(16/32).
__global__ __launch_bounds__(256) void k_attn_mfma(
    const short* __restrict__ qkv, const short* __restrict__ vbT,
    short* __restrict__ y, const float* __restrict__ q_gain) {
  __shared__ short Ks[2][64*72];   // [key][dim]
  __shared__ short Vt[2][64*72];   // [dim][key], key-cols sigma-permuted
  const int t = threadIdx.x;
  const int l = t & 63, w = t >> 6;
  const int lrow = l & 15, g = l >> 4, lk8 = g * 8;
  const int bid = blockIdx.x;
  int qt = bid & 15;
  const int h = (bid >> 4) & 15, b = bid >> 8;
  if (b & 1) qt = 15 - qt;   // balance: co-resident pairs sum to constant tile count
  const int kh = h >> 2;
  bf16x8 qf[2][2];   // [qra][k-half]; Q as B-operand (col = q-row)
#pragma unroll
  for (int qra = 0; qra < 2; ++qra) {
    int qrow_g = b*NSEQ + qt*128 + qra*64 + w*16 + lrow;
#pragma unroll
    for (int hf = 0; hf < 2; ++hf)
      qf[qra][hf] = *(const bf16x8*)(qkv + (size_t)qrow_g*QKVN + h*HDIM + hf*32 + lk8);
  }
  // ---- Q rmsnorm + rope + gain (raw Q from GEMM; once per block) ----
  {
    const float qsc = q_gain[h] * QSCALE;
    float invf[8];
#pragma unroll
    for (int j = 0; j < 8; ++j)
      invf[j] = expf(-(float)(g*8 + j) * (LN_10000 / 32.0f));
#pragma unroll
    for (int qra = 0; qra < 2; ++qra) {
      float v0[8], v1[8];
      float ss = 0.f;
#pragma unroll
      for (int j = 0; j < 8; ++j) {
        v0[j] = b2f(qf[qra][0][j]);
        v1[j] = b2f(qf[qra][1][j]);
        ss += v0[j]*v0[j] + v1[j]*v1[j];
      }
      ss += __shfl_xor(ss, 16);
      ss += __shfl_xor(ss, 32);
      float rr = rsqrtf(ss * (1.0f/64.0f) + RMS_EPS);
      float s = (float)(qt*128 + qra*64 + w*16 + lrow);
#pragma unroll
      for (int j = 0; j < 8; ++j) {
        float fr = s * invf[j];
        float co = cosf(fr), si = sinf(fr);
        float a = v0[j]*rr, c = v1[j]*rr;
        qf[qra][0][j] = f2b((a*co + c*si) * qsc);
        qf[qra][1][j] = f2b((c*co - a*si) * qsc);
      }
    }
  }
  const int r0a = t >> 3;
  const int d0a = (t & 7) * 8;
  const int mseg = t & 7;
  // sigma-permuted V column base for this 8-key chunk
  const int vb0 = (mseg >> 2)*32 + (mseg & 1)*16 + ((mseg >> 1) & 1)*4;
  const short* kgbase = qkv + 1024 + (size_t)kh*HDIM;
  const short* vgbase = vbT + (size_t)((b*NKVH + kh)*HDIM)*NSEQ;
  bf16x8 kr0, kr1, vr0, vr1;
#define LOADKV(KT) do { \
    kr0 = *(const bf16x8*)(kgbase + (size_t)(b*NSEQ + (KT)*64 + r0a)*QKVN + d0a); \
    kr1 = *(const bf16x8*)(kgbase + (size_t)(b*NSEQ + (KT)*64 + r0a + 32)*QKVN + d0a); \
    vr0 = *(const bf16x8*)(vgbase + (size_t)r0a*NSEQ + (KT)*64 + d0a); \
    vr1 = *(const bf16x8*)(vgbase + (size_t)(r0a + 32)*NSEQ + (KT)*64 + d0a); \
  } while (0)
  float m_i[2] = {-INFINITY, -INFINITY};
  float l_i[2] = {0.f, 0.f};
  f32x4 O[2][4];
#pragma unroll
  for (int qra = 0; qra < 2; ++qra)
#pragma unroll
    for (int db = 0; db < 4; ++db) O[qra][db] = 0.f;
  const int ktmax = 2*qt + 1;
  LOADKV(0);
  for (int kt = 0; kt <= ktmax; ++kt) {
    const int buf = kt & 1;
    *(bf16x8*)&Ks[buf][r0a*72 + d0a] = kr0;
    *(bf16x8*)&Ks[buf][(r0a + 32)*72 + d0a] = kr1;
    {  // V: sigma-permuted columns -> two b64 writes per 8-key chunk per row
      short4v* v0p = (short4v*)&vr0;
      short4v* v1p = (short4v*)&vr1;
      *(short4v*)&Vt[buf][r0a*72 + vb0]            = v0p[0];
      *(short4v*)&Vt[buf][r0a*72 + vb0 + 8]        = v0p[1];
      *(short4v*)&Vt[buf][(r0a + 32)*72 + vb0]     = v1p[0];
      *(short4v*)&Vt[buf][(r0a + 32)*72 + vb0 + 8] = v1p[1];
    }
    __syncthreads();
    if (kt < ktmax) LOADKV(kt + 1);   // async prefetch: lands during compute below
    // K fragments are qra-invariant: read ONCE per tile
    bf16x8 kf[4][2];
#pragma unroll
    for (int nb = 0; nb < 4; ++nb) {
      kf[nb][0] = *(const bf16x8*)&Ks[buf][(nb*16 + lrow)*72 + lk8];
      kf[nb][1] = *(const bf16x8*)&Ks[buf][(nb*16 + lrow)*72 + 32 + lk8];
    }
    const int qra0 = (kt == ktmax) ? 1 : 0;   // q-rows 0..63 fully masked on last tile
    bf16x8 pf[2][2];
#pragma unroll
    for (int qra = 0; qra < 2; ++qra) {
      if (qra >= qra0) {
        f32x4 sc[4];
#pragma unroll
        for (int nb = 0; nb < 4; ++nb) sc[nb] = 0.f;
        __builtin_amdgcn_s_setprio(1);
#pragma unroll
        for (int nb = 0; nb < 4; ++nb) {
          sc[nb] = __builtin_amdgcn_mfma_f32_16x16x32_bf16(kf[nb][0], qf[qra][0], sc[nb], 0, 0, 0);
          sc[nb] = __builtin_amdgcn_mfma_f32_16x16x32_bf16(kf[nb][1], qf[qra][1], sc[nb], 0, 0, 0);
        }
        __builtin_amdgcn_s_setprio(0);
        if (kt >= 2*qt) {   // diagonal tiles: elementwise causal mask
          int qg = qt*128 + qra*64 + w*16 + lrow;
#pragma unroll
          for (int nb = 0; nb < 4; ++nb)
#pragma unroll
            for (int r = 0; r < 4; ++r)
              if (kt*64 + nb*16 + g*4 + r > qg) sc[nb][r] = -INFINITY;
        }
        float rm = sc[0][0];
#pragma unroll
        for (int nb = 0; nb < 4; ++nb)
#pragma unroll
          for (int r = 0; r < 4; ++r) rm = fmaxf(rm, sc[nb][r]);
        rm = fmaxf(rm, __shfl_xor(rm, 16));
        rm = fmaxf(rm, __shfl_xor(rm, 32));
        if (!__all(rm <= m_i[qra] + DEFER_THR)) {
          float mn = fmaxf(m_i[qra], rm);
          float fac = ex2(m_i[qra] - mn);
          l_i[qra] *= fac;
          m_i[qra] = mn;
#pragma unroll
          for (int r = 0; r < 4; ++r) {
            float ff = __shfl(fac, g*4 + r);
#pragma unroll
            for (int db = 0; db < 4; ++db) O[qra][db][r] *= ff;
          }
        }
        float rs = 0.f;
#pragma unroll
        for (int nb = 0; nb < 4; ++nb) {
#pragma unroll
          for (int r = 0; r < 4; ++r) {
            float p = ex2(sc[nb][r] - m_i[qra]);
            sc[nb][r] = p;
            rs += p;
          }
        }
        rs += __shfl_xor(rs, 16);
        rs += __shfl_xor(rs, 32);
        l_i[qra] += rs;
        // ---- in-register P: pf[H] = concat(pk[2H], pk[2H+1]), fully lane-local ----
        unsigned pk[4][2];
#pragma unroll
        for (int nb = 0; nb < 4; ++nb) {
          asm("v_cvt_pk_bf16_f32 %0, %1, %2" : "=v"(pk[nb][0]) : "v"(sc[nb][0]), "v"(sc[nb][1]));
          asm("v_cvt_pk_bf16_f32 %0, %1, %2" : "=v"(pk[nb][1]) : "v"(sc[nb][2]), "v"(sc[nb][3]));
        }
#pragma unroll
        for (int H = 0; H < 2; ++H) {
          union { unsigned u[4]; bf16x8 v; } P;
          P.u[0] = pk[2*H][0];
          P.u[1] = pk[2*H][1];
          P.u[2] = pk[2*H+1][0];
          P.u[3] = pk[2*H+1][1];
          pf[qra][H] = P.v;
        }
      }
    }
    __builtin_amdgcn_s_setprio(1);
#pragma unroll
    for (int db = 0; db < 4; ++db) {
      bf16x8 vf0 = *(const bf16x8*)&Vt[buf][(db*16 + lrow)*72 + lk8];
      bf16x8 vf1 = *(const bf16x8*)&Vt[buf][(db*16 + lrow)*72 + 32 + lk8];
      if (qra0 == 0) {
        O[0][db] = __builtin_amdgcn_mfma_f32_16x16x32_bf16(pf[0][0], vf0, O[0][db], 0, 0, 0);
        O[0][db] = __builtin_amdgcn_mfma_f32_16x16x32_bf16(pf[0][1], vf1, O[0][db], 0, 0, 0);
      }
      O[1][db] = __builtin_amdgcn_mfma_f32_16x16x32_bf16(pf[1][0], vf0, O[1][db], 0, 0, 0);
      O[1][db] = __builtin_amdgcn_mfma_f32_16x16x32_bf16(pf[1][1], vf1, O[1][db], 0, 0, 0);
    }
    __builtin_amdgcn_s_setprio(0);
  }
#undef LOADKV
#pragma unroll
  for (int qra = 0; qra < 2; ++qra) {
    float linv = 1.0f / l_i[qra];
#pragma unroll
    for (int r = 0; r < 4; ++r) {
      float inv = __shfl(linv, g*4 + r);
      int rowo = b*NSEQ + qt*128 + qra*64 + w*16 + g*4 + r;
#pragma unroll
      for (int db = 0; db < 4; ++db)
        y[(size_t)rowo*NDIM + h*HDIM + db*16 + lrow] = f2b(O[qra][db][r] * inv);
    }
  }
}

// --------- K5: x2/v_next -> out(f32) ; mbuf = rmsnorm(x2) bf16 ; block 0 also routes ;
//             bids 4096..5119: transpose down fp32 [512][1024] -> wdn_t bf16 [1024][512] ---------
__global__ __launch_bounds__(256) void k_fuse_vel(
    const short* __restrict__ xr, const short* __restrict__ aout,
    const float* __restrict__ vel, const float* __restrict__ ascale,
    const float* __restrict__ mu, float* __restrict__ out, short* __restrict__ mbuf,
    const int* __restrict__ eids, int* __restrict__ rowmap,
    int* __restrict__ tiletab, int* __restrict__ meta,
    const float* __restrict__ down, short* __restrict__ wdn_t) {
  __shared__ short T[64*66];
  __shared__ float wsum[4];
  __shared__ int cnt[NEXP];
  __shared__ int ctr[NEXP];
  const int t = threadIdx.x;
  if (blockIdx.x >= NTOK) {
    // down-transpose tile: KIN=512, NIN=1024
    const int b2 = blockIdx.x - NTOK;
    const int kt = b2 & 7, nt = (b2 >> 3) & 15, e = b2 >> 7;
    const float* ie = down + (size_t)e*512*1024 + (size_t)(kt*64)*1024 + nt*64;
    short* oe = wdn_t + (size_t)e*1024*512 + (size_t)(nt*64)*512 + kt*64;
    const int r = t >> 4, c = (t & 15) * 4;
#pragma unroll
    for (int p = 0; p < 4; ++p) {
      float4 v = *(const float4*)(ie + (size_t)(p*16 + r)*1024 + c);
      T[(p*16 + r)*66 + c + 0] = f2b(v.x);
      T[(p*16 + r)*66 + c + 1] = f2b(v.y);
      T[(p*16 + r)*66 + c + 2] = f2b(v.z);
      T[(p*16 + r)*66 + c + 3] = f2b(v.w);
    }
    __syncthreads();
#pragma unroll
    for (int p = 0; p < 4; ++p) {
      int rr = p*16 + r;
      short4v o = {T[(c+0)*66 + rr], T[(c+1)*66 + rr], T[(c+2)*66 + rr], T[(c+3)*66 + rr]};
      *(short4v*)(oe + (size_t)rr*512 + c) = o;
    }
    return;
  }
  const int row = blockIdx.x;
  const int d = t * 4;
  const size_t base = (size_t)row * NDIM + d;
  short4v a4 = *(const short4v*)(xr + base);
  short4v o4 = *(const short4v*)(aout + base);
  float4 vv = *(const float4*)(vel + base);
  float4 as = *(const float4*)(ascale + d);
  float4 mu4 = *(const float4*)(mu + d);
  float xs[4], vns[4];
  const float asl[4] = {as.x, as.y, as.z, as.w};
  const float mul[4] = {mu4.x, mu4.y, mu4.z, mu4.w};
  const float vvl[4] = {vv.x, vv.y, vv.z, vv.w};
#pragma unroll
  for (int i = 0; i < 4; ++i) {
    float x1 = b2f(a4[i]) + asl[i] * b2f(o4[i]);
    float muc = fminf(fmaxf(mul[i], 0.5f), 1.5f);
    float vn = fminf(fmaxf(0.95f*vvl[i] - 0.3f*(x1 - muc), -3.f), 3.f);
    xs[i] = x1 + 0.01f*vn;
    vns[i] = vn;
  }
  float4 x2 = {xs[0], xs[1], xs[2], xs[3]};
  float4 vnq = {vns[0], vns[1], vns[2], vns[3]};
  *(float4*)(out + base) = x2;
  *(float4*)(out + (size_t)NTOK*NDIM + base) = vnq;
  float ss = xs[0]*xs[0] + xs[1]*xs[1] + xs[2]*xs[2] + xs[3]*xs[3];
  ss = wred64(ss);
  if ((t & 63) == 0) wsum[t >> 6] = ss;
  __syncthreads();
  float tot = wsum[0] + wsum[1] + wsum[2] + wsum[3];
  float rms = rsqrtf(tot * (1.0f/NDIM) + RMS_EPS);
  short4v m4 = {f2b(xs[0]*rms), f2b(xs[1]*rms), f2b(xs[2]*rms), f2b(xs[3]*rms)};
  *(short4v*)(mbuf + base) = m4;
  // ---- block 0: token routing (consumed by gemm1/gemm2, which launch after this kernel) ----
  if (blockIdx.x == 0) {
    if (t < NEXP) cnt[t] = 0;
    __syncthreads();
    for (int i = t; i < NTOK; i += 256) atomicAdd(&cnt[eids[i]], 1);
    __syncthreads();
    if (t == 0) {
      int off = 0, tile = 0;
      for (int e = 0; e < NEXP; ++e) {
        ctr[e] = off;
        int nt_e = (cnt[e] + 127) >> 7;
        for (int j = 0; j < nt_e; ++j) { tiletab[2*tile] = e; tiletab[2*tile+1] = off + j*128; ++tile; }
        off += cnt[e];
        meta[1 + e] = off;
      }
      meta[0] = tile;
      for (int j = tile; j < MAXTILE; ++j) { tiletab[2*j] = -1; tiletab[2*j+1] = 0; }
    }
    __syncthreads();
    for (int i = t; i < NTOK; i += 256) {
      int e = eids[i];
      int slot = atomicAdd(&ctr[e], 1);
      rowmap[slot] = i;
    }
  }
}

extern "C" void kernel_launch(void* const* d_in, const int* in_sizes, int n_in,
                              void* d_out, int out_size, void* d_ws, size_t ws_size,
                              hipStream_t stream) {
  const float* x      = (const float*)d_in[0];
  const float* x0     = (const float*)d_in[1];
  const float* vel    = (const float*)d_in[2];
  const float* rmix   = (const float*)d_in[3];
  const float* ascale = (const float*)d_in[4];
  const float* mscale = (const float*)d_in[5];
  const float* cq_w   = (const float*)d_in[6];
  const float* ck_w   = (const float*)d_in[7];
  const float* cv_w   = (const float*)d_in[8];
  const float* proj_w = (const float*)d_in[9];
  const float* q_gain = (const float*)d_in[10];
  const float* mu     = (const float*)d_in[11];
  const float* gate_up= (const float*)d_in[12];
  const float* down   = (const float*)d_in[13];
  const int*   eids   = (const int*)d_in[14];
  float* out = (float*)d_out;
  char* base = (char*)d_ws;

  const size_t MB = 1024*1024;
  short* wqkv  = (short*)base;            // [0,3)
  short* wproj = (short*)(base + 3*MB);   // [3,5)
  int*   rowmap  = (int*)(base + 5*MB);   // [5,6)
  int*   tiletab = rowmap + NTOK;
  int*   meta    = tiletab + 2*MAXTILE;
  short* wgu_t = (short*)(base + 6*MB);   // [6,22): interleaved gate/up weights
  short* xr    = (short*)(base + 22*MB);  // [22,30): xr -> hbuf after fuse_vel
  short* hbuf  = xr;
  short* nbuf  = (short*)(base + 30*MB);  // [30,38): n -> y -> mbuf
  short* ybuf  = nbuf;
  short* mbuf  = nbuf;
  short* qkv   = (short*)(base + 38*MB);  // [38,50): qkv -> aout after attn
  short* aout  = qkv;
  short* vbT   = (short*)(base + 50*MB);  // [50,52)
  short* wdn_t = (short*)(base + 46*MB);  // [46,54): dead qkv-tail/vbT after attn (ws>=56MB)

  k_w_prep<<<8704, 256, 0, stream>>>(cq_w, ck_w, cv_w, proj_w, gate_up,
                                     wqkv, wproj, wgu_t, x, x0, rmix, xr, nbuf);
  k_gemm_mfma<0><<<dim3(QKVN/128, NTOK/128), 256, 0, stream>>>(
      nbuf, NDIM, wqkv, NDIM, QKVN, qkv, nullptr, QKVN, nullptr, nullptr, nullptr, nullptr);
  k_k_norm_rope<<<NTOK, 256, 0, stream>>>(qkv, vbT);
  k_attn_mfma<<<NBATCH*NHEAD*(NSEQ/128), 256, 0, stream>>>(qkv, vbT, ybuf, q_gain);
  k_gemm_mfma<0><<<dim3(NDIM/128, NTOK/128), 256, 0, stream>>>(
      ybuf, NDIM, wproj, NDIM, NDIM, aout, nullptr, NDIM, nullptr, nullptr, nullptr, nullptr);
  k_fuse_vel<<<NTOK + 1024, 256, 0, stream>>>(xr, aout, vel, ascale, mu, out, mbuf,
                                              eids, rowmap, tiletab, meta, down, wdn_t);
  k_gemm_mfma<3><<<dim3(1024/128, MAXTILE), 256, 0, stream>>>(
      mbuf, NDIM, wgu_t, NDIM, 1024, hbuf, nullptr, NINTER, rowmap, tiletab, meta, nullptr);
  k_gemm_mfma<2><<<dim3(NDIM/128, MAXTILE), 256, 0, stream>>>(
      hbuf, NINTER, wdn_t, NINTER, NDIM, nullptr, out, NDIM, rowmap, tiletab, meta, mscale);
}

// Round 23
// 202.090 us; speedup vs baseline: 1.6165x; 1.0161x over previous
//
#include <hip/hip_runtime.h>
#include <hip/hip_bf16.h>
#include <math.h>

#define NBATCH 2
#define NSEQ   2048
#define NDIM   1024
#define NHEAD  16
#define NKVH   4
#define HDIM   64
#define KVD    256
#define NEXP   8
#define NINTER 512
#define NTOK   (NBATCH*NSEQ)
#define QKVN   1536
#define MAXTILE 40
#define RMS_EPS 1.1920929e-07f
#define LN_10000 9.210340371976184f
#define LOG2_10000 13.287712379549449f
#define QSCALE (0.125f * 1.44269504088896f)   // 1/sqrt(64) * log2(e), folded into Q
#define DEFER_THR 11.5f                        // log2 domain ~= e^8
#define LOG2E 1.44269504088896f
#define INV2PI 0.15915494309189535f

typedef __attribute__((ext_vector_type(8))) short bf16x8;
typedef __attribute__((ext_vector_type(4))) short short4v;
typedef __attribute__((ext_vector_type(4))) float f32x4;

// compiler-cast bf16 conversion: RNE, clang fuses pairs into v_cvt_pk_bf16_f32
__device__ __forceinline__ short f2b(float f) {
  return __builtin_bit_cast(short, (__bf16)f);
}
__device__ __forceinline__ float b2f(short s) {
  unsigned u = ((unsigned)(unsigned short)s) << 16;
  return __builtin_bit_cast(float, u);
}
__device__ __forceinline__ float ex2(float x) {   // 2^x via v_exp_f32
  float r; asm("v_exp_f32 %0, %1" : "=v"(r) : "v"(x)); return r;
}
// fast sin/cos: x in radians -> revolutions, fract-reduce, HW sin/cos (3 VALU ops each)
__device__ __forceinline__ float fsin(float x) {
  float r = x * INV2PI;
  asm("v_fract_f32 %0, %1" : "=v"(r) : "v"(r));
  asm("v_sin_f32 %0, %1" : "=v"(r) : "v"(r));
  return r;
}
__device__ __forceinline__ float fcos(float x) {
  float r = x * INV2PI;
  asm("v_fract_f32 %0, %1" : "=v"(r) : "v"(r));
  asm("v_cos_f32 %0, %1" : "=v"(r) : "v"(r));
  return r;
}
__device__ __forceinline__ void load_lds16(const short* g, short* l) {
  __builtin_amdgcn_global_load_lds((const __attribute__((address_space(1))) void*)g,
                                   (__attribute__((address_space(3))) void*)l, 16, 0, 0);
}

__device__ __forceinline__ float wred64(float v) {
#pragma unroll
  for (int m = 32; m >= 1; m >>= 1) v += __shfl_xor(v, m);
  return v;
}

// ---- W0: merged prep: cast wqkv/wproj (bids 0..2559) + transpose gate_up interleaved
//      (bids 2560..4607) + resid_rms (bids 4608..8703: xr/n for token bid-4608) ----
__global__ __launch_bounds__(256) void k_w_prep(
    const float* __restrict__ cq, const float* __restrict__ ck,
    const float* __restrict__ cv, const float* __restrict__ pw,
    const float* __restrict__ gate_up,
    short* __restrict__ wqkv, short* __restrict__ wproj, short* __restrict__ wgu_t,
    const float* __restrict__ x, const float* __restrict__ x0,
    const float* __restrict__ rmix, short* __restrict__ xr, short* __restrict__ nrm) {
  __shared__ short T[64*66];
  __shared__ float wsum[4];
  const int bid = blockIdx.x;
  const int t = threadIdx.x;
  if (bid < 2560) {
    const int row = bid;
    const int c = t * 4;
    const float* src; short* dst;
    if (row < 1024)      { src = cq + (size_t)row*NDIM;        dst = wqkv + (size_t)row*NDIM; }
    else if (row < 1280) { src = ck + (size_t)(row-1024)*NDIM; dst = wqkv + (size_t)row*NDIM; }
    else if (row < 1536) { src = cv + (size_t)(row-1280)*NDIM; dst = wqkv + (size_t)row*NDIM; }
    else                 { src = pw + (size_t)(row-1536)*NDIM; dst = wproj + (size_t)(row-1536)*NDIM; }
    float4 v = *(const float4*)(src + c);
    short4v o = {f2b(v.x), f2b(v.y), f2b(v.z), f2b(v.w)};
    *(short4v*)(dst + c) = o;
  } else if (bid < 4608) {
    const int b2 = bid - 2560;
    const int kt = b2 & 15, nt = (b2 >> 4) & 15, e = b2 >> 8;
    const float* ie = gate_up + (size_t)e*1024*1024 + (size_t)(kt*64)*1024 + nt*64;
    short* we = wgu_t + (size_t)e*1024*1024;
    const int r = t >> 4, c = (t & 15) * 4;
#pragma unroll
    for (int p = 0; p < 4; ++p) {
      float4 v = *(const float4*)(ie + (size_t)(p*16 + r)*1024 + c);
      T[(p*16 + r)*66 + c + 0] = f2b(v.x);
      T[(p*16 + r)*66 + c + 1] = f2b(v.y);
      T[(p*16 + r)*66 + c + 2] = f2b(v.z);
      T[(p*16 + r)*66 + c + 3] = f2b(v.w);
    }
    __syncthreads();
#pragma unroll
    for (int p = 0; p < 4; ++p) {
      int rr = p*16 + r;
      int R = nt*64 + rr;            // original gate_up column (0..511 gate, 512..1023 up)
      int Rn = (R < 512) ? ((R & ~15)*2 + (R & 15))
                         : (((R - 512) & ~15)*2 + 16 + (R & 15));
      short4v o = {T[(c+0)*66 + rr], T[(c+1)*66 + rr], T[(c+2)*66 + rr], T[(c+3)*66 + rr]};
      *(short4v*)(we + (size_t)Rn*1024 + kt*64 + c) = o;
    }
  } else {
    // resid_rms for token row = bid - 4608
    const int row = bid - 4608;
    const int d = t * 4;
    const size_t base = (size_t)row * NDIM + d;
    float4 a  = *(const float4*)(x  + base);
    float4 b  = *(const float4*)(x0 + base);
    float4 m0 = *(const float4*)(rmix + d);
    float4 m1 = *(const float4*)(rmix + NDIM + d);
    float4 r;
    r.x = m0.x*a.x + m1.x*b.x;
    r.y = m0.y*a.y + m1.y*b.y;
    r.z = m0.z*a.z + m1.z*b.z;
    r.w = m0.w*a.w + m1.w*b.w;
    float ss = r.x*r.x + r.y*r.y + r.z*r.z + r.w*r.w;
    ss = wred64(ss);
    if ((t & 63) == 0) wsum[t >> 6] = ss;
    __syncthreads();
    float tot = wsum[0] + wsum[1] + wsum[2] + wsum[3];
    float rms = rsqrtf(tot * (1.0f/NDIM) + RMS_EPS);
    short4v xo = {f2b(r.x), f2b(r.y), f2b(r.z), f2b(r.w)};
    short4v no = {f2b(r.x*rms), f2b(r.y*rms), f2b(r.z*rms), f2b(r.w*rms)};
    *(short4v*)(xr + base) = xo;
    *(short4v*)(nrm + base) = no;
  }
}

// ---------------- K2: MFMA GEMM 128x128, BK=32, 2-phase double-buffered staging ----------------
// MODE 0: plain rows -> bf16. MODE 1: gather-A -> bf16. MODE 2: compact-A -> scatter-add fp32.
// MODE 3: gather-A, interleaved gate/up B -> fused silu, compact bf16 h [slots][512].
template <int MODE>
__global__ __launch_bounds__(256) void k_gemm_mfma(
    const short* __restrict__ A, int lda,
    const short* __restrict__ Bw, int K, int N,
    short* __restrict__ Cb, float* __restrict__ Cf, int ldc,
    const int* __restrict__ rowmap, const int* __restrict__ tiletab,
    const int* __restrict__ meta, const float* __restrict__ mscale) {
  __shared__ short sA[2][128*32];
  __shared__ short sB[2][128*32];
  int row0, end = 0x7fffffff, e = 0;
  if (MODE == 0) {
    row0 = blockIdx.y * 128;
  } else {
    e = tiletab[2*blockIdx.y];
    if (e < 0) return;
    row0 = tiletab[2*blockIdx.y + 1];
    end = meta[1 + e];
  }
  const int t = threadIdx.x;
  const int w = t >> 6, l = t & 63;
  const int wr = (w >> 1) * 64, wc = (w & 1) * 64;
  const int lrow = l & 15, lk8 = (l >> 4) * 8;
  const int srow0 = w*16 + (l >> 2);
  const int scol = (l & 3) * 8;
  const short* Bp = Bw + (size_t)e * N * K + (size_t)(blockIdx.x * 128) * K;
  const short* gA0;
  const short* gA1;
  if (MODE == 1 || MODE == 3) {
    int s0 = row0 + srow0;      if (s0 >= NTOK) s0 = NTOK - 1;
    int s1 = row0 + 64 + srow0; if (s1 >= NTOK) s1 = NTOK - 1;
    gA0 = A + (size_t)rowmap[s0] * lda + scol;
    gA1 = A + (size_t)rowmap[s1] * lda + scol;
  } else {
    gA0 = A + (size_t)(row0 + srow0) * lda + scol;
    gA1 = A + (size_t)(row0 + 64 + srow0) * lda + scol;
  }
  const short* gB0 = Bp + (size_t)srow0 * K + scol;
  const short* gB1 = Bp + (size_t)(64 + srow0) * K + scol;
  const int lo0 = (w*16)*32;          // wave-uniform LDS offsets
  const int lo1 = (64 + w*16)*32;
  f32x4 acc[4][4];
#pragma unroll
  for (int m = 0; m < 4; ++m)
#pragma unroll
    for (int n = 0; n < 4; ++n) acc[m][n] = 0.f;
  // prologue: stage tile 0 into buf 0
  load_lds16(gA0, sA[0] + lo0);
  load_lds16(gA1, sA[0] + lo1);
  load_lds16(gB0, sB[0] + lo0);
  load_lds16(gB1, sB[0] + lo1);
  gA0 += 32; gA1 += 32; gB0 += 32; gB1 += 32;
  int cur = 0;
  for (int k0 = 0; k0 < K; k0 += 32) {
    __syncthreads();                 // drains vmcnt: buf[cur] ready; prior reads of buf[cur^1] done
    if (k0 + 32 < K) {               // prefetch next tile into the other buffer
      load_lds16(gA0, sA[cur^1] + lo0);
      load_lds16(gA1, sA[cur^1] + lo1);
      load_lds16(gB0, sB[cur^1] + lo0);
      load_lds16(gB1, sB[cur^1] + lo1);
      gA0 += 32; gA1 += 32; gB0 += 32; gB1 += 32;
    }
    bf16x8 af[4], bfr[4];
#pragma unroll
    for (int m = 0; m < 4; ++m)
      af[m] = *(const bf16x8*)&sA[cur][(wr + m*16 + lrow)*32 + lk8];
#pragma unroll
    for (int n = 0; n < 4; ++n)
      bfr[n] = *(const bf16x8*)&sB[cur][(wc + n*16 + lrow)*32 + lk8];
    __builtin_amdgcn_s_setprio(1);
#pragma unroll
    for (int m = 0; m < 4; ++m)
#pragma unroll
      for (int n = 0; n < 4; ++n)
        acc[m][n] = __builtin_amdgcn_mfma_f32_16x16x32_bf16(af[m], bfr[n], acc[m][n], 0, 0, 0);
    __builtin_amdgcn_s_setprio(0);
    cur ^= 1;
  }
  const int col0 = blockIdx.x * 128;
  if (MODE <= 1) {
#pragma unroll
    for (int m = 0; m < 4; ++m) {
#pragma unroll
      for (int r = 0; r < 4; ++r) {
        int rr = row0 + wr + m*16 + (l >> 4)*4 + r;
        if (rr < end) {
#pragma unroll
          for (int n = 0; n < 4; ++n)
            Cb[(size_t)rr * ldc + col0 + wc + n*16 + lrow] = f2b(acc[m][n][r]);
        }
      }
    }
  } else if (MODE == 2) {
#pragma unroll
    for (int m = 0; m < 4; ++m) {
#pragma unroll
      for (int r = 0; r < 4; ++r) {
        int slot = row0 + wr + m*16 + (l >> 4)*4 + r;
        if (slot < end) {
          int tok = rowmap[slot];
#pragma unroll
          for (int n = 0; n < 4; ++n) {
            int cc = col0 + wc + n*16 + lrow;
            Cf[(size_t)tok * ldc + cc] += mscale[cc] * acc[m][n][r];
          }
        }
      }
    }
  } else {   // MODE 3: interleaved gate/up pairs -> h = silu(g)*u, compact [slots][512]
    const int fbBase = (col0 + wc) >> 5;
#pragma unroll
    for (int m = 0; m < 4; ++m) {
#pragma unroll
      for (int r = 0; r < 4; ++r) {
        int slot = row0 + wr + m*16 + (l >> 4)*4 + r;
        if (slot < end) {
#pragma unroll
          for (int p = 0; p < 2; ++p) {
            float gg = acc[m][2*p][r], uu = acc[m][2*p+1][r];
            float sg = 1.0f / (1.0f + ex2(-LOG2E * gg));
            Cb[(size_t)slot * NINTER + (fbBase + p)*16 + lrow] = f2b(gg * sg * uu);
          }
        }
      }
    }
  }
}

// --------- K3: K-head rmsnorm + rope (Q handled in attn prologue) + V-transpose (bids<256) ---------
__global__ __launch_bounds__(256) void k_k_norm_rope(
    short* __restrict__ qkv, short* __restrict__ vbT) {
  __shared__ short T[64*72];
  const int row = blockIdx.x;          // b*S+s
  const int t = threadIdx.x;
  const int w = t >> 6, lane = t & 63;
  const int s = row & (NSEQ - 1);
  const int fi = lane & 31;
  const float fr = (float)s * ex2(-(float)fi * (LOG2_10000 / 32.0f));
  const float co = fcos(fr), si = fsin(fr);
  if (w < NKVH) {
    short* p = qkv + (size_t)row*QKVN + 1024 + w*HDIM + lane;
    float v = b2f(*p);
    float ssum = wred64(v*v);
    float rr = rsqrtf(ssum * (1.0f/HDIM) + RMS_EPS);
    float vn = v * rr;
    float partner = __shfl_xor(vn, 32);
    float o = (lane < 32) ? (vn*co + partner*si) : (vn*co - partner*si);
    *p = f2b(o);
  }
  // blocks 0..255: additionally transpose one V tile (V columns untouched by norm -> no race)
  if (row < 256) {
    const int st = row & 31, kh = (row >> 5) & 3, b = row >> 7;
#pragma unroll
    for (int i = 0; i < 2; ++i) {
      int c = t + i*256;
      int sV = c >> 3, d0 = (c & 7) * 8;
      bf16x8 v = *(const bf16x8*)(qkv + (size_t)(b*NSEQ + st*64 + sV)*QKVN + 1280 + kh*HDIM + d0);
#pragma unroll
      for (int j = 0; j < 8; ++j) T[(d0 + j)*72 + sV] = v[j];
    }
    __syncthreads();
#pragma unroll
    for (int i = 0; i < 2; ++i) {
      int c = t + i*256;
      int d = c >> 3, s0 = (c & 7) * 8;
      *(bf16x8*)(vbT + (size_t)((b*NKVH + kh)*HDIM + d)*NSEQ + st*64 + s0) = *(bf16x8*)&T[d*72 + s0];
    }
  }
}

// ---------------- K4: causal flash attention, swapped-QK^T MFMA, 128-row Q tiles ----------------
// v10: v9 with FAST trig in the Q prologue (v_exp/v_fract/v_sin/v_cos; libm cosf/sinf cost
//      +8.7us in round 22 — full range-reduction paths).
__global__ __launch_bounds__(256) void k_attn_mfma(
    const short* __restrict__ qkv, const short* __restrict__ vbT,
    short* __restrict__ y, const float* __restrict__ q_gain) {
  __shared__ short Ks[2][64*72];   // [key][dim]
  __shared__ short Vt[2][64*72];   // [dim][key], key-cols sigma-permuted
  const int t = threadIdx.x;
  const int l = t & 63, w = t >> 6;
  const int lrow = l & 15, g = l >> 4, lk8 = g * 8;
  const int bid = blockIdx.x;
  int qt = bid & 15;
  const int h = (bid >> 4) & 15, b = bid >> 8;
  if (b & 1) qt = 15 - qt;   // balance: co-resident pairs sum to constant tile count
  const int kh = h >> 2;
  bf16x8 qf[2][2];   // [qra][k-half]; Q as B-operand (col = q-row)
#pragma unroll
  for (int qra = 0; qra < 2; ++qra) {
    int qrow_g = b*NSEQ + qt*128 + qra*64 + w*16 + lrow;
#pragma unroll
    for (int hf = 0; hf < 2; ++hf)
      qf[qra][hf] = *(const bf16x8*)(qkv + (size_t)qrow_g*QKVN + h*HDIM + hf*32 + lk8);
  }
  // ---- Q rmsnorm + rope + gain (raw Q from GEMM; once per block, fast trig) ----
  {
    const float qsc = q_gain[h] * QSCALE;
    float invf[8];
#pragma unroll
    for (int j = 0; j < 8; ++j)
      invf[j] = ex2(-(float)(g*8 + j) * (LOG2_10000 / 32.0f));
#pragma unroll
    for (int qra = 0; qra < 2; ++qra) {
      float v0[8], v1[8];
      float ss = 0.f;
#pragma unroll
      for (int j = 0; j < 8; ++j) {
        v0[j] = b2f(qf[qra][0][j]);
        v1[j] = b2f(qf[qra][1][j]);
        ss += v0[j]*v0[j] + v1[j]*v1[j];
      }
      ss += __shfl_xor(ss, 16);
      ss += __shfl_xor(ss, 32);
      float rr = rsqrtf(ss * (1.0f/64.0f) + RMS_EPS);
      float s = (float)(qt*128 + qra*64 + w*16 + lrow);
#pragma unroll
      for (int j = 0; j < 8; ++j) {
        float fr = s * invf[j];
        float co = fcos(fr), si = fsin(fr);
        float a = v0[j]*rr, c = v1[j]*rr;
        qf[qra][0][j] = f2b((a*co + c*si) * qsc);
        qf[qra][1][j] = f2b((c*co - a*si) * qsc);
      }
    }
  }
  const int r0a = t >> 3;
  const int d0a = (t & 7) * 8;
  const int mseg = t & 7;
  // sigma-permuted V column base for this 8-key chunk
  const int vb0 = (mseg >> 2)*32 + (mseg & 1)*16 + ((mseg >> 1) & 1)*4;
  const short* kgbase = qkv + 1024 + (size_t)kh*HDIM;
  const short* vgbase = vbT + (size_t)((b*NKVH + kh)*HDIM)*NSEQ;
  bf16x8 kr0, kr1, vr0, vr1;
#define LOADKV(KT) do { \
    kr0 = *(const bf16x8*)(kgbase + (size_t)(b*NSEQ + (KT)*64 + r0a)*QKVN + d0a); \
    kr1 = *(const bf16x8*)(kgbase + (size_t)(b*NSEQ + (KT)*64 + r0a + 32)*QKVN + d0a); \
    vr0 = *(const bf16x8*)(vgbase + (size_t)r0a*NSEQ + (KT)*64 + d0a); \
    vr1 = *(const bf16x8*)(vgbase + (size_t)(r0a + 32)*NSEQ + (KT)*64 + d0a); \
  } while (0)
  float m_i[2] = {-INFINITY, -INFINITY};
  float l_i[2] = {0.f, 0.f};
  f32x4 O[2][4];
#pragma unroll
  for (int qra = 0; qra < 2; ++qra)
#pragma unroll
    for (int db = 0; db < 4; ++db) O[qra][db] = 0.f;
  const int ktmax = 2*qt + 1;
  LOADKV(0);
  for (int kt = 0; kt <= ktmax; ++kt) {
    const int buf = kt & 1;
    *(bf16x8*)&Ks[buf][r0a*72 + d0a] = kr0;
    *(bf16x8*)&Ks[buf][(r0a + 32)*72 + d0a] = kr1;
    {  // V: sigma-permuted columns -> two b64 writes per 8-key chunk per row
      short4v* v0p = (short4v*)&vr0;
      short4v* v1p = (short4v*)&vr1;
      *(short4v*)&Vt[buf][r0a*72 + vb0]            = v0p[0];
      *(short4v*)&Vt[buf][r0a*72 + vb0 + 8]        = v0p[1];
      *(short4v*)&Vt[buf][(r0a + 32)*72 + vb0]     = v1p[0];
      *(short4v*)&Vt[buf][(r0a + 32)*72 + vb0 + 8] = v1p[1];
    }
    __syncthreads();
    if (kt < ktmax) LOADKV(kt + 1);   // async prefetch: lands during compute below
    // K fragments are qra-invariant: read ONCE per tile
    bf16x8 kf[4][2];
#pragma unroll
    for (int nb = 0; nb < 4; ++nb) {
      kf[nb][0] = *(const bf16x8*)&Ks[buf][(nb*16 + lrow)*72 + lk8];
      kf[nb][1] = *(const bf16x8*)&Ks[buf][(nb*16 + lrow)*72 + 32 + lk8];
    }
    const int qra0 = (kt == ktmax) ? 1 : 0;   // q-rows 0..63 fully masked on last tile
    bf16x8 pf[2][2];
#pragma unroll
    for (int qra = 0; qra < 2; ++qra) {
      if (qra >= qra0) {
        f32x4 sc[4];
#pragma unroll
        for (int nb = 0; nb < 4; ++nb) sc[nb] = 0.f;
        __builtin_amdgcn_s_setprio(1);
#pragma unroll
        for (int nb = 0; nb < 4; ++nb) {
          sc[nb] = __builtin_amdgcn_mfma_f32_16x16x32_bf16(kf[nb][0], qf[qra][0], sc[nb], 0, 0, 0);
          sc[nb] = __builtin_amdgcn_mfma_f32_16x16x32_bf16(kf[nb][1], qf[qra][1], sc[nb], 0, 0, 0);
        }
        __builtin_amdgcn_s_setprio(0);
        if (kt >= 2*qt) {   // diagonal tiles: elementwise causal mask
          int qg = qt*128 + qra*64 + w*16 + lrow;
#pragma unroll
          for (int nb = 0; nb < 4; ++nb)
#pragma unroll
            for (int r = 0; r < 4; ++r)
              if (kt*64 + nb*16 + g*4 + r > qg) sc[nb][r] = -INFINITY;
        }
        float rm = sc[0][0];
#pragma unroll
        for (int nb = 0; nb < 4; ++nb)
#pragma unroll
          for (int r = 0; r < 4; ++r) rm = fmaxf(rm, sc[nb][r]);
        rm = fmaxf(rm, __shfl_xor(rm, 16));
        rm = fmaxf(rm, __shfl_xor(rm, 32));
        if (!__all(rm <= m_i[qra] + DEFER_THR)) {
          float mn = fmaxf(m_i[qra], rm);
          float fac = ex2(m_i[qra] - mn);
          l_i[qra] *= fac;
          m_i[qra] = mn;
#pragma unroll
          for (int r = 0; r < 4; ++r) {
            float ff = __shfl(fac, g*4 + r);
#pragma unroll
            for (int db = 0; db < 4; ++db) O[qra][db][r] *= ff;
          }
        }
        float rs = 0.f;
#pragma unroll
        for (int nb = 0; nb < 4; ++nb) {
#pragma unroll
          for (int r = 0; r < 4; ++r) {
            float p = ex2(sc[nb][r] - m_i[qra]);
            sc[nb][r] = p;
            rs += p;
          }
        }
        rs += __shfl_xor(rs, 16);
        rs += __shfl_xor(rs, 32);
        l_i[qra] += rs;
        // ---- in-register P: pf[H] = concat(pk[2H], pk[2H+1]), fully lane-local ----
        unsigned pk[4][2];
#pragma unroll
        for (int nb = 0; nb < 4; ++nb) {
          asm("v_cvt_pk_bf16_f32 %0, %1, %2" : "=v"(pk[nb][0]) : "v"(sc[nb][0]), "v"(sc[nb][1]));
          asm("v_cvt_pk_bf16_f32 %0, %1, %2" : "=v"(pk[nb][1]) : "v"(sc[nb][2]), "v"(sc[nb][3]));
        }
#pragma unroll
        for (int H = 0; H < 2; ++H) {
          union { unsigned u[4]; bf16x8 v; } P;
          P.u[0] = pk[2*H][0];
          P.u[1] = pk[2*H][1];
          P.u[2] = pk[2*H+1][0];
          P.u[3] = pk[2*H+1][1];
          pf[qra][H] = P.v;
        }
      }
    }
    __builtin_amdgcn_s_setprio(1);
#pragma unroll
    for (int db = 0; db < 4; ++db) {
      bf16x8 vf0 = *(const bf16x8*)&Vt[buf][(db*16 + lrow)*72 + lk8];
      bf16x8 vf1 = *(const bf16x8*)&Vt[buf][(db*16 + lrow)*72 + 32 + lk8];
      if (qra0 == 0) {
        O[0][db] = __builtin_amdgcn_mfma_f32_16x16x32_bf16(pf[0][0], vf0, O[0][db], 0, 0, 0);
        O[0][db] = __builtin_amdgcn_mfma_f32_16x16x32_bf16(pf[0][1], vf1, O[0][db], 0, 0, 0);
      }
      O[1][db] = __builtin_amdgcn_mfma_f32_16x16x32_bf16(pf[1][0], vf0, O[1][db], 0, 0, 0);
      O[1][db] = __builtin_amdgcn_mfma_f32_16x16x32_bf16(pf[1][1], vf1, O[1][db], 0, 0, 0);
    }
    __builtin_amdgcn_s_setprio(0);
  }
#undef LOADKV
#pragma unroll
  for (int qra = 0; qra < 2; ++qra) {
    float linv = 1.0f / l_i[qra];
#pragma unroll
    for (int r = 0; r < 4; ++r) {
      float inv = __shfl(linv, g*4 + r);
      int rowo = b*NSEQ + qt*128 + qra*64 + w*16 + g*4 + r;
#pragma unroll
      for (int db = 0; db < 4; ++db)
        y[(size_t)rowo*NDIM + h*HDIM + db*16 + lrow] = f2b(O[qra][db][r] * inv);
    }
  }
}

// --------- K5: x2/v_next -> out(f32) ; mbuf = rmsnorm(x2) bf16 ; block 0 also routes ;
//             bids 4096..5119: transpose down fp32 [512][1024] -> wdn_t bf16 [1024][512] ---------
__global__ __launch_bounds__(256) void k_fuse_vel(
    const short* __restrict__ xr, const short* __restrict__ aout,
    const float* __restrict__ vel, const float* __restrict__ ascale,
    const float* __restrict__ mu, float* __restrict__ out, short* __restrict__ mbuf,
    const int* __restrict__ eids, int* __restrict__ rowmap,
    int* __restrict__ tiletab, int* __restrict__ meta,
    const float* __restrict__ down, short* __restrict__ wdn_t) {
  __shared__ short T[64*66];
  __shared__ float wsum[4];
  __shared__ int cnt[NEXP];
  __shared__ int ctr[NEXP];
  const int t = threadIdx.x;
  if (blockIdx.x >= NTOK) {
    // down-transpose tile: KIN=512, NIN=1024
    const int b2 = blockIdx.x - NTOK;
    const int kt = b2 & 7, nt = (b2 >> 3) & 15, e = b2 >> 7;
    const float* ie = down + (size_t)e*512*1024 + (size_t)(kt*64)*1024 + nt*64;
    short* oe = wdn_t + (size_t)e*1024*512 + (size_t)(nt*64)*512 + kt*64;
    const int r = t >> 4, c = (t & 15) * 4;
#pragma unroll
    for (int p = 0; p < 4; ++p) {
      float4 v = *(const float4*)(ie + (size_t)(p*16 + r)*1024 + c);
      T[(p*16 + r)*66 + c + 0] = f2b(v.x);
      T[(p*16 + r)*66 + c + 1] = f2b(v.y);
      T[(p*16 + r)*66 + c + 2] = f2b(v.z);
      T[(p*16 + r)*66 + c + 3] = f2b(v.w);
    }
    __syncthreads();
#pragma unroll
    for (int p = 0; p < 4; ++p) {
      int rr = p*16 + r;
      short4v o = {T[(c+0)*66 + rr], T[(c+1)*66 + rr], T[(c+2)*66 + rr], T[(c+3)*66 + rr]};
      *(short4v*)(oe + (size_t)rr*512 + c) = o;
    }
    return;
  }
  const int row = blockIdx.x;
  const int d = t * 4;
  const size_t base = (size_t)row * NDIM + d;
  short4v a4 = *(const short4v*)(xr + base);
  short4v o4 = *(const short4v*)(aout + base);
  float4 vv = *(const float4*)(vel + base);
  float4 as = *(const float4*)(ascale + d);
  float4 mu4 = *(const float4*)(mu + d);
  float xs[4], vns[4];
  const float asl[4] = {as.x, as.y, as.z, as.w};
  const float mul[4] = {mu4.x, mu4.y, mu4.z, mu4.w};
  const float vvl[4] = {vv.x, vv.y, vv.z, vv.w};
#pragma unroll
  for (int i = 0; i < 4; ++i) {
    float x1 = b2f(a4[i]) + asl[i] * b2f(o4[i]);
    float muc = fminf(fmaxf(mul[i], 0.5f), 1.5f);
    float vn = fminf(fmaxf(0.95f*vvl[i] - 0.3f*(x1 - muc), -3.f), 3.f);
    xs[i] = x1 + 0.01f*vn;
    vns[i] = vn;
  }
  float4 x2 = {xs[0], xs[1], xs[2], xs[3]};
  float4 vnq = {vns[0], vns[1], vns[2], vns[3]};
  *(float4*)(out + base) = x2;
  *(float4*)(out + (size_t)NTOK*NDIM + base) = vnq;
  float ss = xs[0]*xs[0] + xs[1]*xs[1] + xs[2]*xs[2] + xs[3]*xs[3];
  ss = wred64(ss);
  if ((t & 63) == 0) wsum[t >> 6] = ss;
  __syncthreads();
  float tot = wsum[0] + wsum[1] + wsum[2] + wsum[3];
  float rms = rsqrtf(tot * (1.0f/NDIM) + RMS_EPS);
  short4v m4 = {f2b(xs[0]*rms), f2b(xs[1]*rms), f2b(xs[2]*rms), f2b(xs[3]*rms)};
  *(short4v*)(mbuf + base) = m4;
  // ---- block 0: token routing (consumed by gemm1/gemm2, which launch after this kernel) ----
  if (blockIdx.x == 0) {
    if (t < NEXP) cnt[t] = 0;
    __syncthreads();
    for (int i = t; i < NTOK; i += 256) atomicAdd(&cnt[eids[i]], 1);
    __syncthreads();
    if (t == 0) {
      int off = 0, tile = 0;
      for (int e = 0; e < NEXP; ++e) {
        ctr[e] = off;
        int nt_e = (cnt[e] + 127) >> 7;
        for (int j = 0; j < nt_e; ++j) { tiletab[2*tile] = e; tiletab[2*tile+1] = off + j*128; ++tile; }
        off += cnt[e];
        meta[1 + e] = off;
      }
      meta[0] = tile;
      for (int j = tile; j < MAXTILE; ++j) { tiletab[2*j] = -1; tiletab[2*j+1] = 0; }
    }
    __syncthreads();
    for (int i = t; i < NTOK; i += 256) {
      int e = eids[i];
      int slot = atomicAdd(&ctr[e], 1);
      rowmap[slot] = i;
    }
  }
}

extern "C" void kernel_launch(void* const* d_in, const int* in_sizes, int n_in,
                              void* d_out, int out_size, void* d_ws, size_t ws_size,
                              hipStream_t stream) {
  const float* x      = (const float*)d_in[0];
  const float* x0     = (const float*)d_in[1];
  const float* vel    = (const float*)d_in[2];
  const float* rmix   = (const float*)d_in[3];
  const float* ascale = (const float*)d_in[4];
  const float* mscale = (const float*)d_in[5];
  const float* cq_w   = (const float*)d_in[6];
  const float* ck_w   = (const float*)d_in[7];
  const float* cv_w   = (const float*)d_in[8];
  const float* proj_w = (const float*)d_in[9];
  const float* q_gain = (const float*)d_in[10];
  const float* mu     = (const float*)d_in[11];
  const float* gate_up= (const float*)d_in[12];
  const float* down   = (const float*)d_in[13];
  const int*   eids   = (const int*)d_in[14];
  float* out = (float*)d_out;
  char* base = (char*)d_ws;

  const size_t MB = 1024*1024;
  short* wqkv  = (short*)base;            // [0,3)
  short* wproj = (short*)(base + 3*MB);   // [3,5)
  int*   rowmap  = (int*)(base + 5*MB);   // [5,6)
  int*   tiletab = rowmap + NTOK;
  int*   meta    = tiletab + 2*MAXTILE;
  short* wgu_t = (short*)(base + 6*MB);   // [6,22): interleaved gate/up weights
  short* xr    = (short*)(base + 22*MB);  // [22,30): xr -> hbuf after fuse_vel
  short* hbuf  = xr;
  short* nbuf  = (short*)(base + 30*MB);  // [30,38): n -> y -> mbuf
  short* ybuf  = nbuf;
  short* mbuf  = nbuf;
  short* qkv   = (short*)(base + 38*MB);  // [38,50): qkv -> aout after attn
  short* aout  = qkv;
  short* vbT   = (short*)(base + 50*MB);  // [50,52)
  short* wdn_t = (short*)(base + 46*MB);  // [46,54): dead qkv-tail/vbT after attn (ws>=56MB)

  k_w_prep<<<8704, 256, 0, stream>>>(cq_w, ck_w, cv_w, proj_w, gate_up,
                                     wqkv, wproj, wgu_t, x, x0, rmix, xr, nbuf);
  k_gemm_mfma<0><<<dim3(QKVN/128, NTOK/128), 256, 0, stream>>>(
      nbuf, NDIM, wqkv, NDIM, QKVN, qkv, nullptr, QKVN, nullptr, nullptr, nullptr, nullptr);
  k_k_norm_rope<<<NTOK, 256, 0, stream>>>(qkv, vbT);
  k_attn_mfma<<<NBATCH*NHEAD*(NSEQ/128), 256, 0, stream>>>(qkv, vbT, ybuf, q_gain);
  k_gemm_mfma<0><<<dim3(NDIM/128, NTOK/128), 256, 0, stream>>>(
      ybuf, NDIM, wproj, NDIM, NDIM, aout, nullptr, NDIM, nullptr, nullptr, nullptr, nullptr);
  k_fuse_vel<<<NTOK + 1024, 256, 0, stream>>>(xr, aout, vel, ascale, mu, out, mbuf,
                                              eids, rowmap, tiletab, meta, down, wdn_t);
  k_gemm_mfma<3><<<dim3(1024/128, MAXTILE), 256, 0, stream>>>(
      mbuf, NDIM, wgu_t, NDIM, 1024, hbuf, nullptr, NINTER, rowmap, tiletab, meta, nullptr);
  k_gemm_mfma<2><<<dim3(NDIM/128, MAXTILE), 256, 0, stream>>>(
      hbuf, NINTER, wdn_t, NINTER, NDIM, nullptr, out, NDIM, rowmap, tiletab, meta, mscale);
}